// Round 1
// baseline (8507.278 us; speedup 1.0000x reference)
//
#include <hip/hip_runtime.h>
#include <cstddef>
#include <cstdint>

#define DIN 64
#define HID 128

// ---- order-preserving float<->uint for atomicMax-based segment max ----
__device__ __forceinline__ unsigned encf(float f) {
    unsigned b = __float_as_uint(f);
    return (b & 0x80000000u) ? ~b : (b | 0x80000000u);
}
__device__ __forceinline__ float decf(unsigned u) {
    unsigned b = (u & 0x80000000u) ? (u & 0x7FFFFFFFu) : ~u;
    return __uint_as_float(b);
}

// ---- O = A + B (tiny, for Wroot[0]+Wroot[2] pre-sum) ----
__global__ void matadd_k(const float* __restrict__ a, const float* __restrict__ b,
                         float* __restrict__ o, int n) {
    int i = blockIdx.x * blockDim.x + threadIdx.x;
    if (i < n) o[i] = a[i] + b[i];
}

// ---- scatter-add: AGG[dst] += X[src], D floats per edge ----
template <int D>
__global__ __launch_bounds__(256) void scatter_add_k(const float* __restrict__ X,
                                                     const int* __restrict__ ei,
                                                     float* AGG, int E) {
    constexpr int PER = D / 4;  // float4s per edge
    int idx = blockIdx.x * 256 + threadIdx.x;
    int e = idx / PER;
    int seg = idx % PER;
    if (e >= E) return;
    int s = ei[e];
    int d = ei[E + e];
    const float4 v = *reinterpret_cast<const float4*>(&X[(size_t)s * D + seg * 4]);
    float* p = &AGG[(size_t)d * D + seg * 4];
    atomicAdd(p + 0, v.x);
    atomicAdd(p + 1, v.y);
    atomicAdd(p + 2, v.z);
    atomicAdd(p + 3, v.w);
}

// ---- fused multi-source GEMM: O[N,128] = sum_s A_s[N,K] @ W_s[K,128] + b0 (+ b1), opt ReLU
// Block tile 64 rows x 128 cols, 256 threads, each thread 4 rows x 8 cols.
// In-place O==A0 is safe when K==128: each block reads only the rows it writes,
// and all global reads of those rows complete before the epilogue stores.
template <int NA, bool RELU>
__global__ __launch_bounds__(256) void gemm_fused_k(
    const float* A0, const float* __restrict__ W0,
    const float* A1, const float* __restrict__ W1,
    const float* A2, const float* __restrict__ W2,
    const float* __restrict__ b0, const float* __restrict__ b1,
    float* O, int N, int K) {
    __shared__ float As[64][36];   // [row][k], +4 pad keeps 16B alignment, spreads banks
    __shared__ float Bs[32][128];  // [k][col]
    const int tid = threadIdx.x;
    const int tx = tid & 15;   // col group: cols tx*4..+3 and 64+tx*4..+3
    const int ty = tid >> 4;   // row group: rows ty*4..+3
    const int rowBase = blockIdx.x * 64;

    float bb[8];
#pragma unroll
    for (int j = 0; j < 8; ++j) {
        int col = (j < 4) ? (tx * 4 + j) : (64 + tx * 4 + (j - 4));
        float v = b0[col];
        if (b1) v += b1[col];
        bb[j] = v;
    }
    float acc[4][8];
#pragma unroll
    for (int i = 0; i < 4; ++i)
#pragma unroll
        for (int j = 0; j < 8; ++j) acc[i][j] = (i == 0) ? bb[j] : 0.0f;

    const float* Ap[3] = {A0, A1, A2};
    const float* Wp[3] = {W0, W1, W2};

    for (int s = 0; s < NA; ++s) {
        const float* A = Ap[s];
        const float* __restrict__ W = Wp[s];
        for (int k0 = 0; k0 < K; k0 += 32) {
            // A tile: 64x32, 2 float4 per thread
#pragma unroll
            for (int i = 0; i < 2; ++i) {
                int r = (tid >> 3) + i * 32;
                int c = (tid & 7) * 4;
                int gr = rowBase + r;
                float4 v = make_float4(0.f, 0.f, 0.f, 0.f);
                if (gr < N) v = *reinterpret_cast<const float4*>(&A[(size_t)gr * K + k0 + c]);
                *reinterpret_cast<float4*>(&As[r][c]) = v;
            }
            // B tile: 32x128, 4 float4 per thread
#pragma unroll
            for (int i = 0; i < 4; ++i) {
                int idx = tid + 256 * i;
                int k = idx >> 5;
                int c4 = (idx & 31) * 4;
                *reinterpret_cast<float4*>(&Bs[k][c4]) =
                    *reinterpret_cast<const float4*>(&W[(size_t)(k0 + k) * HID + c4]);
            }
            __syncthreads();
#pragma unroll
            for (int kk = 0; kk < 32; ++kk) {
                float a[4];
#pragma unroll
                for (int i = 0; i < 4; ++i) a[i] = As[ty * 4 + i][kk];
                float4 blo = *reinterpret_cast<const float4*>(&Bs[kk][tx * 4]);
                float4 bhi = *reinterpret_cast<const float4*>(&Bs[kk][64 + tx * 4]);
                float b[8] = {blo.x, blo.y, blo.z, blo.w, bhi.x, bhi.y, bhi.z, bhi.w};
#pragma unroll
                for (int i = 0; i < 4; ++i)
#pragma unroll
                    for (int j = 0; j < 8; ++j) acc[i][j] = fmaf(a[i], b[j], acc[i][j]);
            }
            __syncthreads();
        }
    }
    // add bias to rows 1..3 (row 0 got it at init)
#pragma unroll
    for (int i = 1; i < 4; ++i)
#pragma unroll
        for (int j = 0; j < 8; ++j) acc[i][j] += bb[j];

#pragma unroll
    for (int i = 0; i < 4; ++i) {
        int gr = rowBase + ty * 4 + i;
        if (gr >= N) continue;
        float4 lo, hi;
        lo.x = acc[i][0]; lo.y = acc[i][1]; lo.z = acc[i][2]; lo.w = acc[i][3];
        hi.x = acc[i][4]; hi.y = acc[i][5]; hi.z = acc[i][6]; hi.w = acc[i][7];
        if (RELU) {
            lo.x = fmaxf(lo.x, 0.f); lo.y = fmaxf(lo.y, 0.f);
            lo.z = fmaxf(lo.z, 0.f); lo.w = fmaxf(lo.w, 0.f);
            hi.x = fmaxf(hi.x, 0.f); hi.y = fmaxf(hi.y, 0.f);
            hi.z = fmaxf(hi.z, 0.f); hi.w = fmaxf(hi.w, 0.f);
        }
        *reinterpret_cast<float4*>(&O[(size_t)gr * HID + tx * 4]) = lo;
        *reinterpret_cast<float4*>(&O[(size_t)gr * HID + 64 + tx * 4]) = hi;
    }
}

// ---- segment boundaries via binary search (batch ids are sorted) ----
__global__ void seg_bounds_k(const int* __restrict__ batch, int n, int G,
                             int* __restrict__ starts) {
    int g = blockIdx.x * blockDim.x + threadIdx.x;
    if (g > G) return;
    int lo = 0, hi = n;
    while (lo < hi) {
        int mid = (lo + hi) >> 1;
        if (batch[mid] < g) lo = mid + 1; else hi = mid;
    }
    starts[g] = lo;
}

// ---- segment max: grid (G, SUB), 128 threads = one feature each ----
__global__ __launch_bounds__(128) void seg_max_k(const float* __restrict__ Hf,
                                                 const int* __restrict__ starts,
                                                 unsigned* gmU) {
    int g = blockIdx.x;
    int sub = blockIdx.y;
    int SUB = gridDim.y;
    int f = threadIdx.x;
    int s0 = starts[g], s1 = starts[g + 1];
    int len = s1 - s0;
    if (len <= 0) return;
    int chunk = (len + SUB - 1) / SUB;
    int a = s0 + sub * chunk;
    int b = min(a + chunk, s1);
    if (a >= b) return;
    float m = -__builtin_huge_valf();
    for (int n = a; n < b; ++n) m = fmaxf(m, Hf[(size_t)n * HID + f]);
    atomicMax(&gmU[g * HID + f], encf(m));
}

// ---- per-graph MLP heads + final combine; one thread per graph ----
__global__ void head_k(const unsigned* __restrict__ gmU_pe, const unsigned* __restrict__ gmU_r,
                       const float* __restrict__ W1, const float* __restrict__ b1,
                       const float* __restrict__ W2, const float* __restrict__ b2,
                       const float* __restrict__ oW, const float* __restrict__ ob,
                       float* __restrict__ out, int G) {
    int g = threadIdx.x;
    if (g >= G) return;
    float vals[2];
#pragma unroll
    for (int t = 0; t < 2; ++t) {
        const unsigned* gm = t ? gmU_r : gmU_pe;
        float z[5];
#pragma unroll
        for (int j = 0; j < 5; ++j) z[j] = b1[t * 5 + j];
        for (int f = 0; f < HID; ++f) {
            float x = decf(gm[g * HID + f]);
#pragma unroll
            for (int j = 0; j < 5; ++j) z[j] = fmaf(x, W1[t * HID * 5 + f * 5 + j], z[j]);
        }
        float o = b2[t];
#pragma unroll
        for (int j = 0; j < 5; ++j) o = fmaf(fmaxf(z[j], 0.f), W2[t * 5 + j], o);
        vals[t] = o;
    }
    out[g] = vals[0] * oW[0] + vals[1] * oW[1] + ob[0];
}

extern "C" void kernel_launch(void* const* d_in, const int* in_sizes, int n_in,
                              void* d_out, int out_size, void* d_ws, size_t ws_size,
                              hipStream_t stream) {
    const float* x_pe    = (const float*)d_in[0];
    const float* x_r     = (const float*)d_in[1];
    const int* ei_per    = (const int*)d_in[2];
    const int* ei_rpe    = (const int*)d_in[3];
    const int* ei_rr     = (const int*)d_in[4];
    const int* batch_pe  = (const int*)d_in[5];
    const int* batch_r   = (const int*)d_in[6];
    const float* Wrel1   = (const float*)d_in[7];
    const float* brel1   = (const float*)d_in[8];
    const float* Wroot1  = (const float*)d_in[9];
    const float* Wrel23  = (const float*)d_in[10];
    const float* brel23  = (const float*)d_in[11];
    const float* Wroot23 = (const float*)d_in[12];
    const float* mlp_W1  = (const float*)d_in[13];
    const float* mlp_b1  = (const float*)d_in[14];
    const float* mlp_W2  = (const float*)d_in[15];
    const float* mlp_b2  = (const float*)d_in[16];
    const float* out_W   = (const float*)d_in[17];
    const float* out_b   = (const float*)d_in[18];
    float* out = (float*)d_out;

    const int N_PE = in_sizes[0] / DIN;
    const int N_R  = in_sizes[1] / DIN;
    const int E    = in_sizes[2] / 2;
    const int G    = out_size;
    const int NMAX = (N_PE > N_R) ? N_PE : N_R;
    const size_t SZM = (size_t)NMAX * HID;

    float* B1 = (float*)d_ws;
    float* B2 = B1 + SZM;
    float* B3 = B2 + SZM;
    float* B4 = B3 + SZM;
    float* B5 = B4 + SZM;
    float* wsum1 = B5 + SZM;                 // 64*128
    float* wsum2 = wsum1 + DIN * HID;        // 128*128
    float* wsum3 = wsum2 + HID * HID;        // 128*128
    unsigned* gmU_pe = (unsigned*)(wsum3 + HID * HID);
    unsigned* gmU_r  = gmU_pe + G * HID;
    int* starts_pe = (int*)(gmU_r + G * HID);
    int* starts_r  = starts_pe + (G + 1);

    const int gpe = (N_PE + 63) / 64, grr = (N_R + 63) / 64;

    // pre-sum root weights for the router destination (rel 0 + rel 2)
    matadd_k<<<(DIN * HID + 255) / 256, 256, 0, stream>>>(Wroot1, Wroot1 + 2 * DIN * HID, wsum1, DIN * HID);
    matadd_k<<<(HID * HID + 255) / 256, 256, 0, stream>>>(Wroot23, Wroot23 + 2 * HID * HID, wsum2, HID * HID);
    matadd_k<<<(HID * HID + 255) / 256, 256, 0, stream>>>(Wroot23 + 3 * HID * HID, Wroot23 + 5 * HID * HID, wsum3, HID * HID);

    // ---------- layer 1 (K = 64) ----------
    hipMemsetAsync(B1, 0, (size_t)N_PE * DIN * sizeof(float), stream);
    hipMemsetAsync(B2, 0, (size_t)N_R * DIN * sizeof(float), stream);
    hipMemsetAsync(B3, 0, (size_t)N_R * DIN * sizeof(float), stream);
    {
        int blocks = (E * (DIN / 4) + 255) / 256;
        scatter_add_k<DIN><<<blocks, 256, 0, stream>>>(x_r, ei_rpe, B1, E);   // agg_pe_from_r
        scatter_add_k<DIN><<<blocks, 256, 0, stream>>>(x_pe, ei_per, B2, E);  // agg_r_from_pe
        scatter_add_k<DIN><<<blocks, 256, 0, stream>>>(x_r, ei_rr, B3, E);    // agg_r_from_r
    }
    gemm_fused_k<2, true><<<gpe, 256, 0, stream>>>(B1, Wrel1 + 1 * DIN * HID, x_pe, Wroot1 + 1 * DIN * HID,
                                                   nullptr, nullptr, brel1 + HID, nullptr, B4, N_PE, DIN);
    gemm_fused_k<3, true><<<grr, 256, 0, stream>>>(B2, Wrel1, B3, Wrel1 + 2 * DIN * HID, x_r, wsum1,
                                                   brel1, brel1 + 2 * HID, B5, N_R, DIN);

    // ---------- layer 2 (K = 128), h_pe=B4, h_r=B5 ----------
    hipMemsetAsync(B1, 0, (size_t)N_PE * HID * sizeof(float), stream);
    hipMemsetAsync(B2, 0, (size_t)N_R * HID * sizeof(float), stream);
    hipMemsetAsync(B3, 0, (size_t)N_R * HID * sizeof(float), stream);
    {
        int blocks = (E * (HID / 4) + 255) / 256;
        scatter_add_k<HID><<<blocks, 256, 0, stream>>>(B5, ei_rpe, B1, E);
        scatter_add_k<HID><<<blocks, 256, 0, stream>>>(B4, ei_per, B2, E);
        scatter_add_k<HID><<<blocks, 256, 0, stream>>>(B5, ei_rr, B3, E);
    }
    gemm_fused_k<2, true><<<gpe, 256, 0, stream>>>(B1, Wrel23 + 1 * HID * HID, B4, Wroot23 + 1 * HID * HID,
                                                   nullptr, nullptr, brel23 + HID, nullptr, B1, N_PE, HID);
    gemm_fused_k<3, true><<<grr, 256, 0, stream>>>(B2, Wrel23, B3, Wrel23 + 2 * HID * HID, B5, wsum2,
                                                   brel23, brel23 + 2 * HID, B2, N_R, HID);

    // ---------- layer 3 (K = 128), h_pe=B1, h_r=B2, no ReLU ----------
    hipMemsetAsync(B3, 0, (size_t)N_PE * HID * sizeof(float), stream);
    hipMemsetAsync(B4, 0, (size_t)N_R * HID * sizeof(float), stream);
    hipMemsetAsync(B5, 0, (size_t)N_R * HID * sizeof(float), stream);
    {
        int blocks = (E * (HID / 4) + 255) / 256;
        scatter_add_k<HID><<<blocks, 256, 0, stream>>>(B2, ei_rpe, B3, E);
        scatter_add_k<HID><<<blocks, 256, 0, stream>>>(B1, ei_per, B4, E);
        scatter_add_k<HID><<<blocks, 256, 0, stream>>>(B2, ei_rr, B5, E);
    }
    gemm_fused_k<2, false><<<gpe, 256, 0, stream>>>(B3, Wrel23 + 4 * HID * HID, B1, Wroot23 + 4 * HID * HID,
                                                    nullptr, nullptr, brel23 + 4 * HID, nullptr, B3, N_PE, HID);
    gemm_fused_k<3, false><<<grr, 256, 0, stream>>>(B4, Wrel23 + 3 * HID * HID, B5, Wrel23 + 5 * HID * HID,
                                                    B2, wsum3, brel23 + 3 * HID, brel23 + 5 * HID, B4, N_R, HID);

    // ---------- readout: segment max + MLP heads ----------
    seg_bounds_k<<<1, 128, 0, stream>>>(batch_pe, N_PE, G, starts_pe);
    seg_bounds_k<<<1, 128, 0, stream>>>(batch_r, N_R, G, starts_r);
    hipMemsetAsync(gmU_pe, 0, 2 * (size_t)G * HID * sizeof(unsigned), stream);
    dim3 gs(G, 16);
    seg_max_k<<<gs, 128, 0, stream>>>(B3, starts_pe, gmU_pe);
    seg_max_k<<<gs, 128, 0, stream>>>(B4, starts_r, gmU_r);
    head_k<<<1, 64, 0, stream>>>(gmU_pe, gmU_r, mlp_W1, mlp_b1, mlp_W2, mlp_b2, out_W, out_b, out, G);
}

// Round 2
// 1468.581 us; speedup vs baseline: 5.7929x; 5.7929x over previous
//
#include <hip/hip_runtime.h>
#include <cstddef>
#include <cstdint>

#define DIN 64
#define HID 128

// ---- order-preserving float<->uint for atomicMax-based segment max ----
__device__ __forceinline__ unsigned encf(float f) {
    unsigned b = __float_as_uint(f);
    return (b & 0x80000000u) ? ~b : (b | 0x80000000u);
}
__device__ __forceinline__ float decf(unsigned u) {
    unsigned b = (u & 0x80000000u) ? (u & 0x7FFFFFFFu) : ~u;
    return __uint_as_float(b);
}

// ---- O = A + B (tiny, for Wroot pre-sums) ----
__global__ void matadd_k(const float* __restrict__ a, const float* __restrict__ b,
                         float* __restrict__ o, int n) {
    int i = blockIdx.x * blockDim.x + threadIdx.x;
    if (i < n) o[i] = a[i] + b[i];
}

// ================= CSR build (per relation, keyed by dst) =================
__global__ void hist_k(const int* __restrict__ ei, int E, int* cnt) {
    int e = blockIdx.x * 256 + threadIdx.x;
    if (e < E) atomicAdd(&cnt[ei[E + e]], 1);
}

// exclusive scan, 2048 elems/block (256 thr x 8). Safe in-place.
__global__ __launch_bounds__(256) void scanA_k(const int* __restrict__ in, int* out,
                                               int* partials, int n) {
    __shared__ int sh[256];
    int t = threadIdx.x;
    int base = blockIdx.x * 2048 + t * 8;
    int v[8], s = 0;
#pragma unroll
    for (int i = 0; i < 8; ++i) {
        int idx = base + i;
        v[i] = (idx < n) ? in[idx] : 0;
        s += v[i];
    }
    sh[t] = s;
    __syncthreads();
    for (int off = 1; off < 256; off <<= 1) {
        int val = (t >= off) ? sh[t - off] : 0;
        __syncthreads();
        sh[t] += val;
        __syncthreads();
    }
    int run = sh[t] - s;  // exclusive base for this thread
#pragma unroll
    for (int i = 0; i < 8; ++i) {
        int idx = base + i;
        if (idx < n) out[idx] = run;
        run += v[i];
    }
    if (t == 255) partials[blockIdx.x] = sh[255];
}

__global__ void scanB_k(int* partials, int nb) {
    __shared__ int sh[256];
    int t = threadIdx.x;
    int v = (t < nb) ? partials[t] : 0;
    sh[t] = v;
    __syncthreads();
    for (int off = 1; off < 256; off <<= 1) {
        int val = (t >= off) ? sh[t - off] : 0;
        __syncthreads();
        sh[t] += val;
        __syncthreads();
    }
    if (t < nb) partials[t] = sh[t] - v;
}

__global__ void scanC_k(int* out, const int* __restrict__ partials, int n) {
    int i = blockIdx.x * 256 + threadIdx.x;
    if (i < n) out[i] += partials[i >> 11];
}

__global__ void copy_int_k(const int* __restrict__ a, int* __restrict__ b, int n) {
    int i = blockIdx.x * 256 + threadIdx.x;
    if (i < n) b[i] = a[i];
}

__global__ void fill_k(const int* __restrict__ ei, int E, int* cursor, int* __restrict__ adj) {
    int e = blockIdx.x * 256 + threadIdx.x;
    if (e < E) {
        int pos = atomicAdd(&cursor[ei[E + e]], 1);
        adj[pos] = ei[e];
    }
}

// ---- gather-sum aggregation: AGG[d] = sum_{e in CSR[d]} X[adj[e]] ----
template <int D>
__global__ __launch_bounds__(256) void gather_agg_k(const float* __restrict__ X,
                                                    const int* __restrict__ rowptr,
                                                    const int* __restrict__ adj,
                                                    float* __restrict__ AGG, int N) {
    constexpr int TPN = D / 4;       // threads per node
    constexpr int NPB = 256 / TPN;   // nodes per block
    int node = blockIdx.x * NPB + threadIdx.x / TPN;
    int lane = threadIdx.x % TPN;
    if (node >= N) return;
    int a = rowptr[node], b = rowptr[node + 1];
    float4 acc = make_float4(0.f, 0.f, 0.f, 0.f);
    for (int e = a; e < b; ++e) {
        int s = adj[e];
        const float4 v = *reinterpret_cast<const float4*>(&X[(size_t)s * D + lane * 4]);
        acc.x += v.x; acc.y += v.y; acc.z += v.z; acc.w += v.w;
    }
    *reinterpret_cast<float4*>(&AGG[(size_t)node * D + lane * 4]) = acc;
}

// ---- fused multi-source GEMM: O[N,128] = sum_s A_s[N,K] @ W_s[K,128] + b0 (+ b1), opt ReLU
template <int NA, bool RELU>
__global__ __launch_bounds__(256) void gemm_fused_k(
    const float* A0, const float* __restrict__ W0,
    const float* A1, const float* __restrict__ W1,
    const float* A2, const float* __restrict__ W2,
    const float* __restrict__ b0, const float* __restrict__ b1,
    float* O, int N, int K) {
    __shared__ float As[64][36];
    __shared__ float Bs[32][128];
    const int tid = threadIdx.x;
    const int tx = tid & 15;
    const int ty = tid >> 4;
    const int rowBase = blockIdx.x * 64;

    float bb[8];
#pragma unroll
    for (int j = 0; j < 8; ++j) {
        int col = (j < 4) ? (tx * 4 + j) : (64 + tx * 4 + (j - 4));
        float v = b0[col];
        if (b1) v += b1[col];
        bb[j] = v;
    }
    float acc[4][8];
#pragma unroll
    for (int i = 0; i < 4; ++i)
#pragma unroll
        for (int j = 0; j < 8; ++j) acc[i][j] = (i == 0) ? bb[j] : 0.0f;

    const float* Ap[3] = {A0, A1, A2};
    const float* Wp[3] = {W0, W1, W2};

    for (int s = 0; s < NA; ++s) {
        const float* A = Ap[s];
        const float* __restrict__ W = Wp[s];
        for (int k0 = 0; k0 < K; k0 += 32) {
#pragma unroll
            for (int i = 0; i < 2; ++i) {
                int r = (tid >> 3) + i * 32;
                int c = (tid & 7) * 4;
                int gr = rowBase + r;
                float4 v = make_float4(0.f, 0.f, 0.f, 0.f);
                if (gr < N) v = *reinterpret_cast<const float4*>(&A[(size_t)gr * K + k0 + c]);
                *reinterpret_cast<float4*>(&As[r][c]) = v;
            }
#pragma unroll
            for (int i = 0; i < 4; ++i) {
                int idx = tid + 256 * i;
                int k = idx >> 5;
                int c4 = (idx & 31) * 4;
                *reinterpret_cast<float4*>(&Bs[k][c4]) =
                    *reinterpret_cast<const float4*>(&W[(size_t)(k0 + k) * HID + c4]);
            }
            __syncthreads();
#pragma unroll
            for (int kk = 0; kk < 32; ++kk) {
                float a[4];
#pragma unroll
                for (int i = 0; i < 4; ++i) a[i] = As[ty * 4 + i][kk];
                float4 blo = *reinterpret_cast<const float4*>(&Bs[kk][tx * 4]);
                float4 bhi = *reinterpret_cast<const float4*>(&Bs[kk][64 + tx * 4]);
                float b[8] = {blo.x, blo.y, blo.z, blo.w, bhi.x, bhi.y, bhi.z, bhi.w};
#pragma unroll
                for (int i = 0; i < 4; ++i)
#pragma unroll
                    for (int j = 0; j < 8; ++j) acc[i][j] = fmaf(a[i], b[j], acc[i][j]);
            }
            __syncthreads();
        }
    }
#pragma unroll
    for (int i = 1; i < 4; ++i)
#pragma unroll
        for (int j = 0; j < 8; ++j) acc[i][j] += bb[j];

#pragma unroll
    for (int i = 0; i < 4; ++i) {
        int gr = rowBase + ty * 4 + i;
        if (gr >= N) continue;
        float4 lo, hi;
        lo.x = acc[i][0]; lo.y = acc[i][1]; lo.z = acc[i][2]; lo.w = acc[i][3];
        hi.x = acc[i][4]; hi.y = acc[i][5]; hi.z = acc[i][6]; hi.w = acc[i][7];
        if (RELU) {
            lo.x = fmaxf(lo.x, 0.f); lo.y = fmaxf(lo.y, 0.f);
            lo.z = fmaxf(lo.z, 0.f); lo.w = fmaxf(lo.w, 0.f);
            hi.x = fmaxf(hi.x, 0.f); hi.y = fmaxf(hi.y, 0.f);
            hi.z = fmaxf(hi.z, 0.f); hi.w = fmaxf(hi.w, 0.f);
        }
        *reinterpret_cast<float4*>(&O[(size_t)gr * HID + tx * 4]) = lo;
        *reinterpret_cast<float4*>(&O[(size_t)gr * HID + 64 + tx * 4]) = hi;
    }
}

// ---- segment boundaries via binary search (batch ids are sorted) ----
__global__ void seg_bounds_k(const int* __restrict__ batch, int n, int G,
                             int* __restrict__ starts) {
    int g = blockIdx.x * blockDim.x + threadIdx.x;
    if (g > G) return;
    int lo = 0, hi = n;
    while (lo < hi) {
        int mid = (lo + hi) >> 1;
        if (batch[mid] < g) lo = mid + 1; else hi = mid;
    }
    starts[g] = lo;
}

// ---- segment max: grid (G, SUB), 128 threads = one feature each ----
__global__ __launch_bounds__(128) void seg_max_k(const float* __restrict__ Hf,
                                                 const int* __restrict__ starts,
                                                 unsigned* gmU) {
    int g = blockIdx.x;
    int sub = blockIdx.y;
    int SUB = gridDim.y;
    int f = threadIdx.x;
    int s0 = starts[g], s1 = starts[g + 1];
    int len = s1 - s0;
    if (len <= 0) return;
    int chunk = (len + SUB - 1) / SUB;
    int a = s0 + sub * chunk;
    int b = min(a + chunk, s1);
    if (a >= b) return;
    float m = -__builtin_huge_valf();
    for (int n = a; n < b; ++n) m = fmaxf(m, Hf[(size_t)n * HID + f]);
    atomicMax(&gmU[g * HID + f], encf(m));
}

// ---- per-graph MLP heads + final combine; one thread per graph ----
__global__ void head_k(const unsigned* __restrict__ gmU_pe, const unsigned* __restrict__ gmU_r,
                       const float* __restrict__ W1, const float* __restrict__ b1,
                       const float* __restrict__ W2, const float* __restrict__ b2,
                       const float* __restrict__ oW, const float* __restrict__ ob,
                       float* __restrict__ out, int G) {
    int g = threadIdx.x;
    if (g >= G) return;
    float vals[2];
#pragma unroll
    for (int t = 0; t < 2; ++t) {
        const unsigned* gm = t ? gmU_r : gmU_pe;
        float z[5];
#pragma unroll
        for (int j = 0; j < 5; ++j) z[j] = b1[t * 5 + j];
        for (int f = 0; f < HID; ++f) {
            float x = decf(gm[g * HID + f]);
#pragma unroll
            for (int j = 0; j < 5; ++j) z[j] = fmaf(x, W1[t * HID * 5 + f * 5 + j], z[j]);
        }
        float o = b2[t];
#pragma unroll
        for (int j = 0; j < 5; ++j) o = fmaf(fmaxf(z[j], 0.f), W2[t * 5 + j], o);
        vals[t] = o;
    }
    out[g] = vals[0] * oW[0] + vals[1] * oW[1] + ob[0];
}

extern "C" void kernel_launch(void* const* d_in, const int* in_sizes, int n_in,
                              void* d_out, int out_size, void* d_ws, size_t ws_size,
                              hipStream_t stream) {
    const float* x_pe    = (const float*)d_in[0];
    const float* x_r     = (const float*)d_in[1];
    const int* ei_per    = (const int*)d_in[2];
    const int* ei_rpe    = (const int*)d_in[3];
    const int* ei_rr     = (const int*)d_in[4];
    const int* batch_pe  = (const int*)d_in[5];
    const int* batch_r   = (const int*)d_in[6];
    const float* Wrel1   = (const float*)d_in[7];
    const float* brel1   = (const float*)d_in[8];
    const float* Wroot1  = (const float*)d_in[9];
    const float* Wrel23  = (const float*)d_in[10];
    const float* brel23  = (const float*)d_in[11];
    const float* Wroot23 = (const float*)d_in[12];
    const float* mlp_W1  = (const float*)d_in[13];
    const float* mlp_b1  = (const float*)d_in[14];
    const float* mlp_W2  = (const float*)d_in[15];
    const float* mlp_b2  = (const float*)d_in[16];
    const float* out_W   = (const float*)d_in[17];
    const float* out_b   = (const float*)d_in[18];
    float* out = (float*)d_out;

    const int N_PE = in_sizes[0] / DIN;
    const int N_R  = in_sizes[1] / DIN;
    const int E    = in_sizes[2] / 2;
    const int G    = out_size;
    const int NMAX = (N_PE > N_R) ? N_PE : N_R;
    const size_t SZM = (size_t)NMAX * HID;

    float* B1 = (float*)d_ws;
    float* B2 = B1 + SZM;
    float* B3 = B2 + SZM;
    float* B4 = B3 + SZM;
    float* B5 = B4 + SZM;
    float* wsum1 = B5 + SZM;
    float* wsum2 = wsum1 + DIN * HID;
    float* wsum3 = wsum2 + HID * HID;
    unsigned* gmU_pe = (unsigned*)(wsum3 + HID * HID);
    unsigned* gmU_r  = gmU_pe + G * HID;
    int* starts_pe = (int*)(gmU_r + G * HID);
    int* starts_r  = starts_pe + (G + 1);
    // CSR arrays: 3 relations x (rowptr[N+1] | adj[E] | cursor[N] | partials[64])
    int* csr = starts_r + (G + 1);
    auto csr_rowptr = [&](int r, int Nd) { return csr + (size_t)r * (2 * NMAX + E + 65); };
    // layout within a relation: rowptr (Nd+1), adj (E), cursor (Nd), partials (64)

    const int gpe = (N_PE + 63) / 64, grr = (N_R + 63) / 64;

    // ---- pre-sum root weights for router destination (rel 0 + rel 2) ----
    matadd_k<<<(DIN * HID + 255) / 256, 256, 0, stream>>>(Wroot1, Wroot1 + 2 * DIN * HID, wsum1, DIN * HID);
    matadd_k<<<(HID * HID + 255) / 256, 256, 0, stream>>>(Wroot23, Wroot23 + 2 * HID * HID, wsum2, HID * HID);
    matadd_k<<<(HID * HID + 255) / 256, 256, 0, stream>>>(Wroot23 + 3 * HID * HID, Wroot23 + 5 * HID * HID, wsum3, HID * HID);

    // ---- build CSR per relation (keyed by dst) ----
    int* rp[3];   // rowptr
    int* adj[3];
    const int* eis[3] = {ei_per, ei_rpe, ei_rr};
    const int  Nds[3] = {N_R, N_PE, N_R};
    for (int r = 0; r < 3; ++r) {
        int Nd = Nds[r];
        int* rowptr   = csr_rowptr(r, Nd);
        int* adjp     = rowptr + (Nd + 1);
        int* cursor   = adjp + E;
        int* partials = cursor + Nd;
        rp[r] = rowptr; adj[r] = adjp;
        hipMemsetAsync(rowptr, 0, (Nd + 1) * sizeof(int), stream);
        hist_k<<<(E + 255) / 256, 256, 0, stream>>>(eis[r], E, rowptr);
        int n = Nd + 1;
        int nb = (n + 2047) / 2048;
        scanA_k<<<nb, 256, 0, stream>>>(rowptr, rowptr, partials, n);
        scanB_k<<<1, 256, 0, stream>>>(partials, nb);
        scanC_k<<<nb * 8, 256, 0, stream>>>(rowptr, partials, n);
        copy_int_k<<<(Nd + 255) / 256, 256, 0, stream>>>(rowptr, cursor, Nd);
        fill_k<<<(E + 255) / 256, 256, 0, stream>>>(eis[r], E, cursor, adjp);
    }

    // ---------- layer 1 (K = 64) ----------
    gather_agg_k<DIN><<<(N_PE + 15) / 16, 256, 0, stream>>>(x_r, rp[1], adj[1], B1, N_PE);   // agg_pe_from_r
    gather_agg_k<DIN><<<(N_R + 15) / 16, 256, 0, stream>>>(x_pe, rp[0], adj[0], B2, N_R);    // agg_r_from_pe
    gather_agg_k<DIN><<<(N_R + 15) / 16, 256, 0, stream>>>(x_r, rp[2], adj[2], B3, N_R);     // agg_r_from_r
    gemm_fused_k<2, true><<<gpe, 256, 0, stream>>>(B1, Wrel1 + 1 * DIN * HID, x_pe, Wroot1 + 1 * DIN * HID,
                                                   nullptr, nullptr, brel1 + HID, nullptr, B4, N_PE, DIN);
    gemm_fused_k<3, true><<<grr, 256, 0, stream>>>(B2, Wrel1, B3, Wrel1 + 2 * DIN * HID, x_r, wsum1,
                                                   brel1, brel1 + 2 * HID, B5, N_R, DIN);

    // ---------- layer 2 (K = 128), h_pe=B4, h_r=B5 ----------
    gather_agg_k<HID><<<(N_PE + 7) / 8, 256, 0, stream>>>(B5, rp[1], adj[1], B1, N_PE);
    gather_agg_k<HID><<<(N_R + 7) / 8, 256, 0, stream>>>(B4, rp[0], adj[0], B2, N_R);
    gather_agg_k<HID><<<(N_R + 7) / 8, 256, 0, stream>>>(B5, rp[2], adj[2], B3, N_R);
    gemm_fused_k<2, true><<<gpe, 256, 0, stream>>>(B1, Wrel23 + 1 * HID * HID, B4, Wroot23 + 1 * HID * HID,
                                                   nullptr, nullptr, brel23 + HID, nullptr, B1, N_PE, HID);
    gemm_fused_k<3, true><<<grr, 256, 0, stream>>>(B2, Wrel23, B3, Wrel23 + 2 * HID * HID, B5, wsum2,
                                                   brel23, brel23 + 2 * HID, B2, N_R, HID);

    // ---------- layer 3 (K = 128), h_pe=B1, h_r=B2, no ReLU ----------
    gather_agg_k<HID><<<(N_PE + 7) / 8, 256, 0, stream>>>(B2, rp[1], adj[1], B3, N_PE);
    gather_agg_k<HID><<<(N_R + 7) / 8, 256, 0, stream>>>(B1, rp[0], adj[0], B4, N_R);
    gather_agg_k<HID><<<(N_R + 7) / 8, 256, 0, stream>>>(B2, rp[2], adj[2], B5, N_R);
    gemm_fused_k<2, false><<<gpe, 256, 0, stream>>>(B3, Wrel23 + 4 * HID * HID, B1, Wroot23 + 4 * HID * HID,
                                                    nullptr, nullptr, brel23 + 4 * HID, nullptr, B3, N_PE, HID);
    gemm_fused_k<3, false><<<grr, 256, 0, stream>>>(B4, Wrel23 + 3 * HID * HID, B5, Wrel23 + 5 * HID * HID,
                                                    B2, wsum3, brel23 + 3 * HID, brel23 + 5 * HID, B4, N_R, HID);

    // ---------- readout: segment max + MLP heads ----------
    seg_bounds_k<<<1, 128, 0, stream>>>(batch_pe, N_PE, G, starts_pe);
    seg_bounds_k<<<1, 128, 0, stream>>>(batch_r, N_R, G, starts_r);
    hipMemsetAsync(gmU_pe, 0, 2 * (size_t)G * HID * sizeof(unsigned), stream);
    dim3 gs(G, 16);
    seg_max_k<<<gs, 128, 0, stream>>>(B3, starts_pe, gmU_pe);
    seg_max_k<<<gs, 128, 0, stream>>>(B4, starts_r, gmU_r);
    head_k<<<1, 64, 0, stream>>>(gmU_pe, gmU_r, mlp_W1, mlp_b1, mlp_W2, mlp_b2, out_W, out_b, out, G);
}

// Round 3
// 1164.370 us; speedup vs baseline: 7.3063x; 1.2613x over previous
//
#include <hip/hip_runtime.h>
#include <cstddef>
#include <cstdint>

#define DIN 64
#define HID 128

typedef _Float16 half4v __attribute__((ext_vector_type(4)));
typedef _Float16 half8v __attribute__((ext_vector_type(8)));
typedef float f32x16 __attribute__((ext_vector_type(16)));

// ---- order-preserving float<->uint for atomicMax-based segment max ----
__device__ __forceinline__ unsigned encf(float f) {
    unsigned b = __float_as_uint(f);
    return (b & 0x80000000u) ? ~b : (b | 0x80000000u);
}
__device__ __forceinline__ float decf(unsigned u) {
    unsigned b = (u & 0x80000000u) ? (u & 0x7FFFFFFFu) : ~u;
    return __uint_as_float(b);
}

// ---- O = A + B (tiny, for Wroot pre-sums) ----
__global__ void matadd_k(const float* __restrict__ a, const float* __restrict__ b,
                         float* __restrict__ o, int n) {
    int i = blockIdx.x * blockDim.x + threadIdx.x;
    if (i < n) o[i] = a[i] + b[i];
}

// ---- convert+transpose weights: src [M][K][128] fp32 -> dst [M][128][K] f16 ----
__global__ void conv_w_k(const float* __restrict__ src, _Float16* __restrict__ dst,
                         int K, int M) {
    int i = blockIdx.x * 256 + threadIdx.x;
    int total = M * K * HID;
    if (i >= total) return;
    int m = i / (K * HID);
    int rem = i % (K * HID);
    int k = rem / HID;
    int col = rem % HID;
    dst[(size_t)m * HID * K + (size_t)col * K + k] = (_Float16)src[i];
}

// ================= CSR build (per relation, keyed by dst) =================
__global__ void hist_k(const int* __restrict__ ei, int E, int* cnt) {
    int e = blockIdx.x * 256 + threadIdx.x;
    if (e < E) atomicAdd(&cnt[ei[E + e]], 1);
}

__global__ __launch_bounds__(256) void scanA_k(const int* __restrict__ in, int* out,
                                               int* partials, int n) {
    __shared__ int sh[256];
    int t = threadIdx.x;
    int base = blockIdx.x * 2048 + t * 8;
    int v[8], s = 0;
#pragma unroll
    for (int i = 0; i < 8; ++i) {
        int idx = base + i;
        v[i] = (idx < n) ? in[idx] : 0;
        s += v[i];
    }
    sh[t] = s;
    __syncthreads();
    for (int off = 1; off < 256; off <<= 1) {
        int val = (t >= off) ? sh[t - off] : 0;
        __syncthreads();
        sh[t] += val;
        __syncthreads();
    }
    int run = sh[t] - s;
#pragma unroll
    for (int i = 0; i < 8; ++i) {
        int idx = base + i;
        if (idx < n) out[idx] = run;
        run += v[i];
    }
    if (t == 255) partials[blockIdx.x] = sh[255];
}

__global__ void scanB_k(int* partials, int nb) {
    __shared__ int sh[256];
    int t = threadIdx.x;
    int v = (t < nb) ? partials[t] : 0;
    sh[t] = v;
    __syncthreads();
    for (int off = 1; off < 256; off <<= 1) {
        int val = (t >= off) ? sh[t - off] : 0;
        __syncthreads();
        sh[t] += val;
        __syncthreads();
    }
    if (t < nb) partials[t] = sh[t] - v;
}

__global__ void scanC_k(int* out, const int* __restrict__ partials, int n) {
    int i = blockIdx.x * 256 + threadIdx.x;
    if (i < n) out[i] += partials[i >> 11];
}

__global__ void copy_int_k(const int* __restrict__ a, int* __restrict__ b, int n) {
    int i = blockIdx.x * 256 + threadIdx.x;
    if (i < n) b[i] = a[i];
}

__global__ void fill_k(const int* __restrict__ ei, int E, int* cursor, int* __restrict__ adj) {
    int e = blockIdx.x * 256 + threadIdx.x;
    if (e < E) {
        int pos = atomicAdd(&cursor[ei[E + e]], 1);
        adj[pos] = ei[e];
    }
}

// ---- gather-sum aggregation: AGG[d] = sum_{e in CSR[d]} X[adj[e]] ----
template <int D>
__global__ __launch_bounds__(256) void gather_agg_k(const float* __restrict__ X,
                                                    const int* __restrict__ rowptr,
                                                    const int* __restrict__ adj,
                                                    float* __restrict__ AGG, int N) {
    constexpr int TPN = D / 4;
    constexpr int NPB = 256 / TPN;
    int node = blockIdx.x * NPB + threadIdx.x / TPN;
    int lane = threadIdx.x % TPN;
    if (node >= N) return;
    int a = rowptr[node], b = rowptr[node + 1];
    float4 acc = make_float4(0.f, 0.f, 0.f, 0.f);
    for (int e = a; e < b; ++e) {
        int s = adj[e];
        const float4 v = *reinterpret_cast<const float4*>(&X[(size_t)s * D + lane * 4]);
        acc.x += v.x; acc.y += v.y; acc.z += v.z; acc.w += v.w;
    }
    *reinterpret_cast<float4*>(&AGG[(size_t)node * D + lane * 4]) = acc;
}

// ======================= MFMA GEMM =======================
// O[N,128] = sum_s A_s[N,K] @ W_s[K,128] + b0 (+ b1), optional ReLU.
// A fp32 in global, converted to f16 on the fly; W pre-converted f16, transposed [col][K].
// fp32 accumulate via v_mfma_f32_32x32x16_f16. Block: 128 rows x 128 cols, 4 waves (2x2),
// each wave 64x64 = 4 MFMA C-tiles (16 f32 acc regs each).
// In-place O==A0 is safe when K==128: each block reads only the rows it writes.
template <int NA, bool RELU>
__global__ __launch_bounds__(256) void gemm_mfma_k(
    const float* A0, const _Float16* __restrict__ W0,
    const float* A1, const _Float16* __restrict__ W1,
    const float* A2, const _Float16* __restrict__ W2,
    const float* __restrict__ b0, const float* __restrict__ b1,
    float* O, int N, int K) {
    // frag-ready A chunk: region (rt*2+t) of 64 lanes x 16B.
    // lane l in region holds A[rowBase + rt*32 + (l&31)][k0 + t*16 + (l>>5)*8 .. +8] as f16.
    __shared__ _Float16 Alds[128 * 32];  // 8 KB
    const int tid = threadIdx.x;
    const int lane = tid & 63;
    const int w = tid >> 6;
    const int wr = w & 1;
    const int wc = w >> 1;
    const int rowBase = blockIdx.x * 128;

    f32x16 acc[2][2];
#pragma unroll
    for (int r = 0; r < 2; ++r)
#pragma unroll
        for (int c = 0; c < 2; ++c)
#pragma unroll
            for (int q = 0; q < 16; ++q) acc[r][c][q] = 0.0f;

    const float* Ap[3] = {A0, A1, A2};
    const _Float16* Wp[3] = {W0, W1, W2};

    const int srow = tid >> 1;          // staging row 0..127
    const int skh = (tid & 1) * 16;     // staging k-half within 32-chunk
    const int srt = srow >> 5;
    const int sl5 = srow & 31;

    for (int s = 0; s < NA; ++s) {
        const float* A = Ap[s];
        const _Float16* __restrict__ Wt = Wp[s];
        for (int k0 = 0; k0 < K; k0 += 32) {
            // ---- stage A: 128 rows x 32 k, fp32 -> f16, frag-ready layout ----
            {
                int gr = rowBase + srow;
                const float* src = A + (size_t)gr * K + k0 + skh;
#pragma unroll
                for (int i = 0; i < 4; ++i) {
                    int k4 = skh + i * 4;
                    float4 v = make_float4(0.f, 0.f, 0.f, 0.f);
                    if (gr < N) v = *reinterpret_cast<const float4*>(src + i * 4);
                    half4v h;
                    h.x = (_Float16)v.x; h.y = (_Float16)v.y;
                    h.z = (_Float16)v.z; h.w = (_Float16)v.w;
                    int t = (k4 >> 4) & 1;
                    int lh = (k4 >> 3) & 1;
                    int j = k4 & 7;
                    *(half4v*)((char*)Alds + (((srt * 2 + t) * 64 + sl5 + lh * 32) * 16 + j * 2)) = h;
                }
            }
            __syncthreads();
            // ---- compute: 2 k-steps of 16 ----
#pragma unroll
            for (int t = 0; t < 2; ++t) {
                half8v a[2], b[2];
#pragma unroll
                for (int r = 0; r < 2; ++r) {
                    int rt = wr * 2 + r;
                    a[r] = *(const half8v*)((char*)Alds + (((rt * 2 + t) * 64 + lane) * 16));
                }
#pragma unroll
                for (int c = 0; c < 2; ++c) {
                    int col = wc * 64 + c * 32 + (lane & 31);
                    b[c] = *(const half8v*)&Wt[(size_t)col * K + k0 + t * 16 + (lane >> 5) * 8];
                }
#pragma unroll
                for (int r = 0; r < 2; ++r)
#pragma unroll
                    for (int c = 0; c < 2; ++c)
                        acc[r][c] = __builtin_amdgcn_mfma_f32_32x32x16_f16(a[r], b[c], acc[r][c], 0, 0, 0);
            }
            __syncthreads();
        }
    }

    // ---- epilogue: bias (+ReLU), store. C/D: col=lane&31, row=(q&3)+8*(q>>2)+4*(lane>>5) ----
    float bias[2];
#pragma unroll
    for (int c = 0; c < 2; ++c) {
        int col = wc * 64 + c * 32 + (lane & 31);
        float v = b0[col];
        if (b1) v += b1[col];
        bias[c] = v;
    }
#pragma unroll
    for (int r = 0; r < 2; ++r) {
        int rb = rowBase + wr * 64 + r * 32 + 4 * (lane >> 5);
#pragma unroll
        for (int c = 0; c < 2; ++c) {
            int col = wc * 64 + c * 32 + (lane & 31);
#pragma unroll
            for (int q = 0; q < 16; ++q) {
                int row = rb + (q & 3) + 8 * (q >> 2);
                if (row < N) {
                    float v = acc[r][c][q] + bias[c];
                    if (RELU) v = fmaxf(v, 0.f);
                    O[(size_t)row * HID + col] = v;
                }
            }
        }
    }
}

// ---- segment boundaries via binary search (batch ids are sorted) ----
__global__ void seg_bounds_k(const int* __restrict__ batch, int n, int G,
                             int* __restrict__ starts) {
    int g = blockIdx.x * blockDim.x + threadIdx.x;
    if (g > G) return;
    int lo = 0, hi = n;
    while (lo < hi) {
        int mid = (lo + hi) >> 1;
        if (batch[mid] < g) lo = mid + 1; else hi = mid;
    }
    starts[g] = lo;
}

// ---- segment max: grid (G, SUB), 128 threads = one feature each ----
__global__ __launch_bounds__(128) void seg_max_k(const float* __restrict__ Hf,
                                                 const int* __restrict__ starts,
                                                 unsigned* gmU) {
    int g = blockIdx.x;
    int sub = blockIdx.y;
    int SUB = gridDim.y;
    int f = threadIdx.x;
    int s0 = starts[g], s1 = starts[g + 1];
    int len = s1 - s0;
    if (len <= 0) return;
    int chunk = (len + SUB - 1) / SUB;
    int a = s0 + sub * chunk;
    int b = min(a + chunk, s1);
    if (a >= b) return;
    float m = -__builtin_huge_valf();
    for (int n = a; n < b; ++n) m = fmaxf(m, Hf[(size_t)n * HID + f]);
    atomicMax(&gmU[g * HID + f], encf(m));
}

// ---- per-graph MLP heads + final combine; one thread per graph ----
__global__ void head_k(const unsigned* __restrict__ gmU_pe, const unsigned* __restrict__ gmU_r,
                       const float* __restrict__ W1, const float* __restrict__ b1,
                       const float* __restrict__ W2, const float* __restrict__ b2,
                       const float* __restrict__ oW, const float* __restrict__ ob,
                       float* __restrict__ out, int G) {
    int g = threadIdx.x;
    if (g >= G) return;
    float vals[2];
#pragma unroll
    for (int t = 0; t < 2; ++t) {
        const unsigned* gm = t ? gmU_r : gmU_pe;
        float z[5];
#pragma unroll
        for (int j = 0; j < 5; ++j) z[j] = b1[t * 5 + j];
        for (int f = 0; f < HID; ++f) {
            float x = decf(gm[g * HID + f]);
#pragma unroll
            for (int j = 0; j < 5; ++j) z[j] = fmaf(x, W1[t * HID * 5 + f * 5 + j], z[j]);
        }
        float o = b2[t];
#pragma unroll
        for (int j = 0; j < 5; ++j) o = fmaf(fmaxf(z[j], 0.f), W2[t * 5 + j], o);
        vals[t] = o;
    }
    out[g] = vals[0] * oW[0] + vals[1] * oW[1] + ob[0];
}

extern "C" void kernel_launch(void* const* d_in, const int* in_sizes, int n_in,
                              void* d_out, int out_size, void* d_ws, size_t ws_size,
                              hipStream_t stream) {
    const float* x_pe    = (const float*)d_in[0];
    const float* x_r     = (const float*)d_in[1];
    const int* ei_per    = (const int*)d_in[2];
    const int* ei_rpe    = (const int*)d_in[3];
    const int* ei_rr     = (const int*)d_in[4];
    const int* batch_pe  = (const int*)d_in[5];
    const int* batch_r   = (const int*)d_in[6];
    const float* Wrel1   = (const float*)d_in[7];
    const float* brel1   = (const float*)d_in[8];
    const float* Wroot1  = (const float*)d_in[9];
    const float* Wrel23  = (const float*)d_in[10];
    const float* brel23  = (const float*)d_in[11];
    const float* Wroot23 = (const float*)d_in[12];
    const float* mlp_W1  = (const float*)d_in[13];
    const float* mlp_b1  = (const float*)d_in[14];
    const float* mlp_W2  = (const float*)d_in[15];
    const float* mlp_b2  = (const float*)d_in[16];
    const float* out_W   = (const float*)d_in[17];
    const float* out_b   = (const float*)d_in[18];
    float* out = (float*)d_out;

    const int N_PE = in_sizes[0] / DIN;
    const int N_R  = in_sizes[1] / DIN;
    const int E    = in_sizes[2] / 2;
    const int G    = out_size;
    const int NMAX = (N_PE > N_R) ? N_PE : N_R;
    const size_t SZM = (size_t)NMAX * HID;

    float* B1 = (float*)d_ws;
    float* B2 = B1 + SZM;
    float* B3 = B2 + SZM;
    float* B4 = B3 + SZM;
    float* B5 = B4 + SZM;
    float* wsum1 = B5 + SZM;
    float* wsum2 = wsum1 + DIN * HID;
    float* wsum3 = wsum2 + HID * HID;
    unsigned* gmU_pe = (unsigned*)(wsum3 + HID * HID);
    unsigned* gmU_r  = gmU_pe + G * HID;
    int* starts_pe = (int*)(gmU_r + G * HID);
    int* starts_r  = starts_pe + (G + 1);
    int* csr = starts_r + (G + 1);
    auto csr_rowptr = [&](int r) { return csr + (size_t)r * (2 * NMAX + E + 65); };
    // f16 transposed weights pool (after CSR region)
    _Float16* wt = (_Float16*)(csr + 3 * (size_t)(2 * NMAX + E + 65));
    _Float16* wt_rel1    = wt;                              // 3 x 128 x 64
    _Float16* wt_root1pe = wt_rel1 + 3 * DIN * HID;         // 128 x 64
    _Float16* wt_wsum1   = wt_root1pe + DIN * HID;          // 128 x 64
    _Float16* wt_rel23   = wt_wsum1 + DIN * HID;            // 6 x 128 x 128
    _Float16* wt_root23  = wt_rel23 + 6 * HID * HID;        // 6 x 128 x 128
    _Float16* wt_wsum2   = wt_root23 + 6 * HID * HID;       // 128 x 128
    _Float16* wt_wsum3   = wt_wsum2 + HID * HID;            // 128 x 128

    const int gg = (NMAX + 127) / 128;  // N_PE == N_R here; per-call grids below
    const int gpe = (N_PE + 127) / 128, grr = (N_R + 127) / 128;
    (void)gg;

    // ---- pre-sum root weights for router destination (rel 0 + rel 2) ----
    matadd_k<<<(DIN * HID + 255) / 256, 256, 0, stream>>>(Wroot1, Wroot1 + 2 * DIN * HID, wsum1, DIN * HID);
    matadd_k<<<(HID * HID + 255) / 256, 256, 0, stream>>>(Wroot23, Wroot23 + 2 * HID * HID, wsum2, HID * HID);
    matadd_k<<<(HID * HID + 255) / 256, 256, 0, stream>>>(Wroot23 + 3 * HID * HID, Wroot23 + 5 * HID * HID, wsum3, HID * HID);

    // ---- convert weights to f16, transposed [col][K] ----
    conv_w_k<<<(3 * DIN * HID + 255) / 256, 256, 0, stream>>>(Wrel1, wt_rel1, DIN, 3);
    conv_w_k<<<(DIN * HID + 255) / 256, 256, 0, stream>>>(Wroot1 + 1 * DIN * HID, wt_root1pe, DIN, 1);
    conv_w_k<<<(DIN * HID + 255) / 256, 256, 0, stream>>>(wsum1, wt_wsum1, DIN, 1);
    conv_w_k<<<(6 * HID * HID + 255) / 256, 256, 0, stream>>>(Wrel23, wt_rel23, HID, 6);
    conv_w_k<<<(6 * HID * HID + 255) / 256, 256, 0, stream>>>(Wroot23, wt_root23, HID, 6);
    conv_w_k<<<(HID * HID + 255) / 256, 256, 0, stream>>>(wsum2, wt_wsum2, HID, 1);
    conv_w_k<<<(HID * HID + 255) / 256, 256, 0, stream>>>(wsum3, wt_wsum3, HID, 1);

    // ---- build CSR per relation (keyed by dst) ----
    int* rp[3];
    int* adj[3];
    const int* eis[3] = {ei_per, ei_rpe, ei_rr};
    const int  Nds[3] = {N_R, N_PE, N_R};
    for (int r = 0; r < 3; ++r) {
        int Nd = Nds[r];
        int* rowptr   = csr_rowptr(r);
        int* adjp     = rowptr + (Nd + 1);
        int* cursor   = adjp + E;
        int* partials = cursor + Nd;
        rp[r] = rowptr; adj[r] = adjp;
        hipMemsetAsync(rowptr, 0, (Nd + 1) * sizeof(int), stream);
        hist_k<<<(E + 255) / 256, 256, 0, stream>>>(eis[r], E, rowptr);
        int n = Nd + 1;
        int nb = (n + 2047) / 2048;
        scanA_k<<<nb, 256, 0, stream>>>(rowptr, rowptr, partials, n);
        scanB_k<<<1, 256, 0, stream>>>(partials, nb);
        scanC_k<<<nb * 8, 256, 0, stream>>>(rowptr, partials, n);
        copy_int_k<<<(Nd + 255) / 256, 256, 0, stream>>>(rowptr, cursor, Nd);
        fill_k<<<(E + 255) / 256, 256, 0, stream>>>(eis[r], E, cursor, adjp);
    }

    // ---------- layer 1 (K = 64) ----------
    gather_agg_k<DIN><<<(N_PE + 15) / 16, 256, 0, stream>>>(x_r, rp[1], adj[1], B1, N_PE);
    gather_agg_k<DIN><<<(N_R + 15) / 16, 256, 0, stream>>>(x_pe, rp[0], adj[0], B2, N_R);
    gather_agg_k<DIN><<<(N_R + 15) / 16, 256, 0, stream>>>(x_r, rp[2], adj[2], B3, N_R);
    gemm_mfma_k<2, true><<<gpe, 256, 0, stream>>>(B1, wt_rel1 + 1 * DIN * HID, x_pe, wt_root1pe,
                                                  nullptr, nullptr, brel1 + HID, nullptr, B4, N_PE, DIN);
    gemm_mfma_k<3, true><<<grr, 256, 0, stream>>>(B2, wt_rel1, B3, wt_rel1 + 2 * DIN * HID, x_r, wt_wsum1,
                                                  brel1, brel1 + 2 * HID, B5, N_R, DIN);

    // ---------- layer 2 (K = 128), h_pe=B4, h_r=B5 ----------
    gather_agg_k<HID><<<(N_PE + 7) / 8, 256, 0, stream>>>(B5, rp[1], adj[1], B1, N_PE);
    gather_agg_k<HID><<<(N_R + 7) / 8, 256, 0, stream>>>(B4, rp[0], adj[0], B2, N_R);
    gather_agg_k<HID><<<(N_R + 7) / 8, 256, 0, stream>>>(B5, rp[2], adj[2], B3, N_R);
    gemm_mfma_k<2, true><<<gpe, 256, 0, stream>>>(B1, wt_rel23 + 1 * HID * HID, B4, wt_root23 + 1 * HID * HID,
                                                  nullptr, nullptr, brel23 + HID, nullptr, B1, N_PE, HID);
    gemm_mfma_k<3, true><<<grr, 256, 0, stream>>>(B2, wt_rel23, B3, wt_rel23 + 2 * HID * HID, B5, wt_wsum2,
                                                  brel23, brel23 + 2 * HID, B2, N_R, HID);

    // ---------- layer 3 (K = 128), h_pe=B1, h_r=B2, no ReLU ----------
    gather_agg_k<HID><<<(N_PE + 7) / 8, 256, 0, stream>>>(B2, rp[1], adj[1], B3, N_PE);
    gather_agg_k<HID><<<(N_R + 7) / 8, 256, 0, stream>>>(B1, rp[0], adj[0], B4, N_R);
    gather_agg_k<HID><<<(N_R + 7) / 8, 256, 0, stream>>>(B2, rp[2], adj[2], B5, N_R);
    gemm_mfma_k<2, false><<<gpe, 256, 0, stream>>>(B3, wt_rel23 + 4 * HID * HID, B1, wt_root23 + 4 * HID * HID,
                                                   nullptr, nullptr, brel23 + 4 * HID, nullptr, B3, N_PE, HID);
    gemm_mfma_k<3, false><<<grr, 256, 0, stream>>>(B4, wt_rel23 + 3 * HID * HID, B5, wt_rel23 + 5 * HID * HID,
                                                   B2, wt_wsum3, brel23 + 3 * HID, brel23 + 5 * HID, B4, N_R, HID);

    // ---------- readout: segment max + MLP heads ----------
    seg_bounds_k<<<1, 128, 0, stream>>>(batch_pe, N_PE, G, starts_pe);
    seg_bounds_k<<<1, 128, 0, stream>>>(batch_r, N_R, G, starts_r);
    hipMemsetAsync(gmU_pe, 0, 2 * (size_t)G * HID * sizeof(unsigned), stream);
    dim3 gs(G, 16);
    seg_max_k<<<gs, 128, 0, stream>>>(B3, starts_pe, gmU_pe);
    seg_max_k<<<gs, 128, 0, stream>>>(B4, starts_r, gmU_r);
    head_k<<<1, 64, 0, stream>>>(gmU_pe, gmU_r, mlp_W1, mlp_b1, mlp_W2, mlp_b2, out_W, out_b, out, G);
}

// Round 4
// 983.505 us; speedup vs baseline: 8.6500x; 1.1839x over previous
//
#include <hip/hip_runtime.h>
#include <cstddef>
#include <cstdint>

#define DIN 64
#define HID 128

typedef _Float16 half4v __attribute__((ext_vector_type(4)));
typedef _Float16 half8v __attribute__((ext_vector_type(8)));
typedef float f32x16 __attribute__((ext_vector_type(16)));

// ---- order-preserving float<->uint for atomicMax-based segment max ----
__device__ __forceinline__ unsigned encf(float f) {
    unsigned b = __float_as_uint(f);
    return (b & 0x80000000u) ? ~b : (b | 0x80000000u);
}
__device__ __forceinline__ float decf(unsigned u) {
    unsigned b = (u & 0x80000000u) ? (u & 0x7FFFFFFFu) : ~u;
    return __uint_as_float(b);
}

// ---- O = A + B (tiny, for Wroot pre-sums) ----
__global__ void matadd_k(const float* __restrict__ a, const float* __restrict__ b,
                         float* __restrict__ o, int n) {
    int i = blockIdx.x * blockDim.x + threadIdx.x;
    if (i < n) o[i] = a[i] + b[i];
}

// ---- convert fp32 -> f16 flat (vectorized x4) ----
__global__ void conv_x_k(const float* __restrict__ src, _Float16* __restrict__ dst, int n4) {
    int i = blockIdx.x * 256 + threadIdx.x;
    if (i >= n4) return;
    float4 v = *reinterpret_cast<const float4*>(&src[i * 4]);
    half4v h;
    h.x = (_Float16)v.x; h.y = (_Float16)v.y; h.z = (_Float16)v.z; h.w = (_Float16)v.w;
    *reinterpret_cast<half4v*>(&dst[i * 4]) = h;
}

// ---- convert+transpose weights: src [M][K][128] fp32 -> dst [M][128][K] f16 ----
__global__ void conv_w_k(const float* __restrict__ src, _Float16* __restrict__ dst,
                         int K, int M) {
    int i = blockIdx.x * 256 + threadIdx.x;
    int total = M * K * HID;
    if (i >= total) return;
    int m = i / (K * HID);
    int rem = i % (K * HID);
    int k = rem / HID;
    int col = rem % HID;
    dst[(size_t)m * HID * K + (size_t)col * K + k] = (_Float16)src[i];
}

// ================= CSR build (per relation, keyed by dst) =================
__global__ void hist_k(const int* __restrict__ ei, int E, int* cnt) {
    int e = blockIdx.x * 256 + threadIdx.x;
    if (e < E) atomicAdd(&cnt[ei[E + e]], 1);
}

__global__ __launch_bounds__(256) void scanA_k(const int* __restrict__ in, int* out,
                                               int* partials, int n) {
    __shared__ int sh[256];
    int t = threadIdx.x;
    int base = blockIdx.x * 2048 + t * 8;
    int v[8], s = 0;
#pragma unroll
    for (int i = 0; i < 8; ++i) {
        int idx = base + i;
        v[i] = (idx < n) ? in[idx] : 0;
        s += v[i];
    }
    sh[t] = s;
    __syncthreads();
    for (int off = 1; off < 256; off <<= 1) {
        int val = (t >= off) ? sh[t - off] : 0;
        __syncthreads();
        sh[t] += val;
        __syncthreads();
    }
    int run = sh[t] - s;
#pragma unroll
    for (int i = 0; i < 8; ++i) {
        int idx = base + i;
        if (idx < n) out[idx] = run;
        run += v[i];
    }
    if (t == 255) partials[blockIdx.x] = sh[255];
}

__global__ void scanB_k(int* partials, int nb) {
    __shared__ int sh[256];
    int t = threadIdx.x;
    int v = (t < nb) ? partials[t] : 0;
    sh[t] = v;
    __syncthreads();
    for (int off = 1; off < 256; off <<= 1) {
        int val = (t >= off) ? sh[t - off] : 0;
        __syncthreads();
        sh[t] += val;
        __syncthreads();
    }
    if (t < nb) partials[t] = sh[t] - v;
}

__global__ void scanC_k(int* out, const int* __restrict__ partials, int n) {
    int i = blockIdx.x * 256 + threadIdx.x;
    if (i < n) out[i] += partials[i >> 11];
}

__global__ void copy_int_k(const int* __restrict__ a, int* __restrict__ b, int n) {
    int i = blockIdx.x * 256 + threadIdx.x;
    if (i < n) b[i] = a[i];
}

__global__ void fill_k(const int* __restrict__ ei, int E, int* cursor, int* __restrict__ adj) {
    int e = blockIdx.x * 256 + threadIdx.x;
    if (e < E) {
        int pos = atomicAdd(&cursor[ei[E + e]], 1);
        adj[pos] = ei[e];
    }
}

// ---- gather-sum aggregation (f16 in / f16 out, fp32 accumulate) ----
template <int D>
__global__ __launch_bounds__(256) void gather_agg_k(const _Float16* __restrict__ X,
                                                    const int* __restrict__ rowptr,
                                                    const int* __restrict__ adj,
                                                    _Float16* __restrict__ AGG, int N) {
    constexpr int TPN = D / 8;       // 16 B of f16 per lane
    constexpr int NPB = 256 / TPN;
    int node = blockIdx.x * NPB + threadIdx.x / TPN;
    int lane = threadIdx.x % TPN;
    if (node >= N) return;
    int a = rowptr[node], b = rowptr[node + 1];
    float acc[8] = {0.f, 0.f, 0.f, 0.f, 0.f, 0.f, 0.f, 0.f};
    for (int e = a; e < b; ++e) {
        int s = adj[e];
        half8v v = *reinterpret_cast<const half8v*>(&X[(size_t)s * D + lane * 8]);
#pragma unroll
        for (int i = 0; i < 8; ++i) acc[i] += (float)v[i];
    }
    half8v o;
#pragma unroll
    for (int i = 0; i < 8; ++i) o[i] = (_Float16)acc[i];
    *reinterpret_cast<half8v*>(&AGG[(size_t)node * D + lane * 8]) = o;
}

// ======================= MFMA GEMM (f16 activations end-to-end) =======================
// O[N,128] = sum_s A_s[N,K] @ W_s[K,128] + b0 (+ b1), optional ReLU.
// A f16 [N][K]; W f16 transposed [col][K]; fp32 accumulate (v_mfma_f32_32x32x16_f16).
// Block: 128 rows x 128 cols, 4 waves (2x2), each wave 64x64 (4x 32x32 C-tiles).
// Register-prefetch of the next A chunk overlaps global load latency with MFMA.
// In-place O==A_s is safe: each block reads only the rows it writes; all global
// reads complete (waited for the LDS writes) before the final barrier + epilogue.
template <int NA, bool RELU>
__global__ __launch_bounds__(256) void gemm_mfma_k(
    const _Float16* A0, const _Float16* __restrict__ W0,
    const _Float16* A1, const _Float16* __restrict__ W1,
    const _Float16* A2, const _Float16* __restrict__ W2,
    const float* __restrict__ b0, const float* __restrict__ b1,
    _Float16* O, int N, int K) {
    // frag-ready LDS: region R = (srow>>5)*2 + t, lane l holds
    // A[rowBase + (R>>1)*32 + (l&31)][k0 + (R&1)*16 + (l>>5)*8 .. +8]
    __shared__ _Float16 Alds[128 * 32];  // 8 KB
    const int tid = threadIdx.x;
    const int lane = tid & 63;
    const int w = tid >> 6;
    const int wr = w & 1;
    const int wc = w >> 1;
    const int rowBase = blockIdx.x * 128;

    f32x16 acc[2][2];
#pragma unroll
    for (int r = 0; r < 2; ++r)
#pragma unroll
        for (int c = 0; c < 2; ++c)
#pragma unroll
            for (int q = 0; q < 16; ++q) acc[r][c][q] = 0.0f;

    const _Float16* Ap[3] = {A0, A1, A2};
    const _Float16* Wp[3] = {W0, W1, W2};

    // staging map: lane-consecutive rows -> conflict-free 16B LDS writes
    const int srow = tid & 127;          // 0..127
    const int skh = (tid >> 7) * 16;     // k-offset 0 or 16
    const int gr = rowBase + srow;
    const bool rowOK = (gr < N);
    const int sR = (srow >> 5) * 2 + (skh >> 4);
    const int sl5 = srow & 31;
    _Float16* ldsw0 = &Alds[(sR * 64 + sl5) * 8];
    _Float16* ldsw1 = &Alds[(sR * 64 + sl5 + 32) * 8];

    const int CPS = K / 32;           // k-chunks per source
    const int total = NA * CPS;

    auto ld_chunk = [&](int c, half8v& h0, half8v& h1) {
        int s = c / CPS;
        int k0 = (c % CPS) * 32;
        half8v z = {};
        h0 = z; h1 = z;
        if (rowOK) {
            const _Float16* p = Ap[s] + (size_t)gr * K + k0 + skh;
            h0 = *reinterpret_cast<const half8v*>(p);
            h1 = *reinterpret_cast<const half8v*>(p + 8);
        }
    };

    half8v p0, p1, n0, n1;
    ld_chunk(0, p0, p1);

    for (int c = 0; c < total; ++c) {
        *reinterpret_cast<half8v*>(ldsw0) = p0;
        *reinterpret_cast<half8v*>(ldsw1) = p1;
        __syncthreads();
        if (c + 1 < total) ld_chunk(c + 1, n0, n1);
        {
            int s = c / CPS;
            int k0 = (c % CPS) * 32;
            const _Float16* __restrict__ Wt = Wp[s];
#pragma unroll
            for (int t = 0; t < 2; ++t) {
                half8v a[2], b[2];
#pragma unroll
                for (int r = 0; r < 2; ++r) {
                    int R = (wr * 2 + r) * 2 + t;
                    a[r] = *reinterpret_cast<const half8v*>(&Alds[(R * 64 + lane) * 8]);
                }
#pragma unroll
                for (int cc = 0; cc < 2; ++cc) {
                    int col = wc * 64 + cc * 32 + (lane & 31);
                    b[cc] = *reinterpret_cast<const half8v*>(
                        &Wt[(size_t)col * K + k0 + t * 16 + (lane >> 5) * 8]);
                }
#pragma unroll
                for (int r = 0; r < 2; ++r)
#pragma unroll
                    for (int cc = 0; cc < 2; ++cc)
                        acc[r][cc] = __builtin_amdgcn_mfma_f32_32x32x16_f16(a[r], b[cc], acc[r][cc], 0, 0, 0);
            }
        }
        __syncthreads();
        p0 = n0; p1 = n1;
    }

    // ---- epilogue: bias (+ReLU), store f16. C/D: col=lane&31, row=(q&3)+8*(q>>2)+4*(lane>>5) ----
    float bias[2];
#pragma unroll
    for (int c = 0; c < 2; ++c) {
        int col = wc * 64 + c * 32 + (lane & 31);
        float v = b0[col];
        if (b1) v += b1[col];
        bias[c] = v;
    }
#pragma unroll
    for (int r = 0; r < 2; ++r) {
        int rb = rowBase + wr * 64 + r * 32 + 4 * (lane >> 5);
#pragma unroll
        for (int c = 0; c < 2; ++c) {
            int col = wc * 64 + c * 32 + (lane & 31);
#pragma unroll
            for (int q = 0; q < 16; ++q) {
                int row = rb + (q & 3) + 8 * (q >> 2);
                if (row < N) {
                    float v = acc[r][c][q] + bias[c];
                    if (RELU) v = fmaxf(v, 0.f);
                    O[(size_t)row * HID + col] = (_Float16)v;
                }
            }
        }
    }
}

// ---- segment boundaries via binary search (batch ids are sorted) ----
__global__ void seg_bounds_k(const int* __restrict__ batch, int n, int G,
                             int* __restrict__ starts) {
    int g = blockIdx.x * blockDim.x + threadIdx.x;
    if (g > G) return;
    int lo = 0, hi = n;
    while (lo < hi) {
        int mid = (lo + hi) >> 1;
        if (batch[mid] < g) lo = mid + 1; else hi = mid;
    }
    starts[g] = lo;
}

// ---- segment max over f16 features: grid (G, SUB), 128 threads ----
__global__ __launch_bounds__(128) void seg_max_k(const _Float16* __restrict__ Hf,
                                                 const int* __restrict__ starts,
                                                 unsigned* gmU) {
    int g = blockIdx.x;
    int sub = blockIdx.y;
    int SUB = gridDim.y;
    int f = threadIdx.x;
    int s0 = starts[g], s1 = starts[g + 1];
    int len = s1 - s0;
    if (len <= 0) return;
    int chunk = (len + SUB - 1) / SUB;
    int a = s0 + sub * chunk;
    int b = min(a + chunk, s1);
    if (a >= b) return;
    float m = -__builtin_huge_valf();
    for (int n = a; n < b; ++n) m = fmaxf(m, (float)Hf[(size_t)n * HID + f]);
    atomicMax(&gmU[g * HID + f], encf(m));
}

// ---- per-graph MLP heads + final combine; one thread per graph ----
__global__ void head_k(const unsigned* __restrict__ gmU_pe, const unsigned* __restrict__ gmU_r,
                       const float* __restrict__ W1, const float* __restrict__ b1,
                       const float* __restrict__ W2, const float* __restrict__ b2,
                       const float* __restrict__ oW, const float* __restrict__ ob,
                       float* __restrict__ out, int G) {
    int g = threadIdx.x;
    if (g >= G) return;
    float vals[2];
#pragma unroll
    for (int t = 0; t < 2; ++t) {
        const unsigned* gm = t ? gmU_r : gmU_pe;
        float z[5];
#pragma unroll
        for (int j = 0; j < 5; ++j) z[j] = b1[t * 5 + j];
        for (int f = 0; f < HID; ++f) {
            float x = decf(gm[g * HID + f]);
#pragma unroll
            for (int j = 0; j < 5; ++j) z[j] = fmaf(x, W1[t * HID * 5 + f * 5 + j], z[j]);
        }
        float o = b2[t];
#pragma unroll
        for (int j = 0; j < 5; ++j) o = fmaf(fmaxf(z[j], 0.f), W2[t * 5 + j], o);
        vals[t] = o;
    }
    out[g] = vals[0] * oW[0] + vals[1] * oW[1] + ob[0];
}

extern "C" void kernel_launch(void* const* d_in, const int* in_sizes, int n_in,
                              void* d_out, int out_size, void* d_ws, size_t ws_size,
                              hipStream_t stream) {
    const float* x_pe    = (const float*)d_in[0];
    const float* x_r     = (const float*)d_in[1];
    const int* ei_per    = (const int*)d_in[2];
    const int* ei_rpe    = (const int*)d_in[3];
    const int* ei_rr     = (const int*)d_in[4];
    const int* batch_pe  = (const int*)d_in[5];
    const int* batch_r   = (const int*)d_in[6];
    const float* Wrel1   = (const float*)d_in[7];
    const float* brel1   = (const float*)d_in[8];
    const float* Wroot1  = (const float*)d_in[9];
    const float* Wrel23  = (const float*)d_in[10];
    const float* brel23  = (const float*)d_in[11];
    const float* Wroot23 = (const float*)d_in[12];
    const float* mlp_W1  = (const float*)d_in[13];
    const float* mlp_b1  = (const float*)d_in[14];
    const float* mlp_W2  = (const float*)d_in[15];
    const float* mlp_b2  = (const float*)d_in[16];
    const float* out_W   = (const float*)d_in[17];
    const float* out_b   = (const float*)d_in[18];
    float* out = (float*)d_out;

    const int N_PE = in_sizes[0] / DIN;
    const int N_R  = in_sizes[1] / DIN;
    const int E    = in_sizes[2] / 2;
    const int G    = out_size;
    const int NMAX = (N_PE > N_R) ? N_PE : N_R;
    const size_t SZM = (size_t)NMAX * HID;

    // ---- workspace layout (f16 activations) ----
    _Float16* H1 = (_Float16*)d_ws;
    _Float16* H2 = H1 + SZM;
    _Float16* H3 = H2 + SZM;
    _Float16* H4 = H3 + SZM;
    _Float16* H5 = H4 + SZM;
    _Float16* xh_pe = H5 + SZM;                       // N_PE x 64
    _Float16* xh_r  = xh_pe + (size_t)N_PE * DIN;     // N_R x 64
    float* wsum1 = (float*)(xh_r + (size_t)N_R * DIN);
    float* wsum2 = wsum1 + DIN * HID;
    float* wsum3 = wsum2 + HID * HID;
    _Float16* wt_rel1    = (_Float16*)(wsum3 + HID * HID);  // 3 x 128 x 64
    _Float16* wt_root1pe = wt_rel1 + 3 * DIN * HID;
    _Float16* wt_wsum1   = wt_root1pe + DIN * HID;
    _Float16* wt_rel23   = wt_wsum1 + DIN * HID;            // 6 x 128 x 128
    _Float16* wt_root23  = wt_rel23 + 6 * HID * HID;        // 6 x 128 x 128
    _Float16* wt_wsum2   = wt_root23 + 6 * HID * HID;
    _Float16* wt_wsum3   = wt_wsum2 + HID * HID;
    unsigned* gmU_pe = (unsigned*)(wt_wsum3 + HID * HID);
    unsigned* gmU_r  = gmU_pe + G * HID;
    int* starts_pe = (int*)(gmU_r + G * HID);
    int* starts_r  = starts_pe + (G + 1);
    int* csr = starts_r + (G + 1);
    auto csr_rowptr = [&](int r) { return csr + (size_t)r * (2 * NMAX + E + 65); };

    const int gpe = (N_PE + 127) / 128, grr = (N_R + 127) / 128;

    // ---- pre-sum root weights for router destination (rel 0 + rel 2) ----
    matadd_k<<<(DIN * HID + 255) / 256, 256, 0, stream>>>(Wroot1, Wroot1 + 2 * DIN * HID, wsum1, DIN * HID);
    matadd_k<<<(HID * HID + 255) / 256, 256, 0, stream>>>(Wroot23, Wroot23 + 2 * HID * HID, wsum2, HID * HID);
    matadd_k<<<(HID * HID + 255) / 256, 256, 0, stream>>>(Wroot23 + 3 * HID * HID, Wroot23 + 5 * HID * HID, wsum3, HID * HID);

    // ---- convert inputs + weights to f16 ----
    conv_x_k<<<((N_PE * DIN / 4) + 255) / 256, 256, 0, stream>>>(x_pe, xh_pe, N_PE * DIN / 4);
    conv_x_k<<<((N_R * DIN / 4) + 255) / 256, 256, 0, stream>>>(x_r, xh_r, N_R * DIN / 4);
    conv_w_k<<<(3 * DIN * HID + 255) / 256, 256, 0, stream>>>(Wrel1, wt_rel1, DIN, 3);
    conv_w_k<<<(DIN * HID + 255) / 256, 256, 0, stream>>>(Wroot1 + 1 * DIN * HID, wt_root1pe, DIN, 1);
    conv_w_k<<<(DIN * HID + 255) / 256, 256, 0, stream>>>(wsum1, wt_wsum1, DIN, 1);
    conv_w_k<<<(6 * HID * HID + 255) / 256, 256, 0, stream>>>(Wrel23, wt_rel23, HID, 6);
    conv_w_k<<<(6 * HID * HID + 255) / 256, 256, 0, stream>>>(Wroot23, wt_root23, HID, 6);
    conv_w_k<<<(HID * HID + 255) / 256, 256, 0, stream>>>(wsum2, wt_wsum2, HID, 1);
    conv_w_k<<<(HID * HID + 255) / 256, 256, 0, stream>>>(wsum3, wt_wsum3, HID, 1);

    // ---- build CSR per relation (keyed by dst) ----
    int* rp[3];
    int* adj[3];
    const int* eis[3] = {ei_per, ei_rpe, ei_rr};
    const int  Nds[3] = {N_R, N_PE, N_R};
    for (int r = 0; r < 3; ++r) {
        int Nd = Nds[r];
        int* rowptr   = csr_rowptr(r);
        int* adjp     = rowptr + (Nd + 1);
        int* cursor   = adjp + E;
        int* partials = cursor + Nd;
        rp[r] = rowptr; adj[r] = adjp;
        hipMemsetAsync(rowptr, 0, (Nd + 1) * sizeof(int), stream);
        hist_k<<<(E + 255) / 256, 256, 0, stream>>>(eis[r], E, rowptr);
        int n = Nd + 1;
        int nb = (n + 2047) / 2048;
        scanA_k<<<nb, 256, 0, stream>>>(rowptr, rowptr, partials, n);
        scanB_k<<<1, 256, 0, stream>>>(partials, nb);
        scanC_k<<<nb * 8, 256, 0, stream>>>(rowptr, partials, n);
        copy_int_k<<<(Nd + 255) / 256, 256, 0, stream>>>(rowptr, cursor, Nd);
        fill_k<<<(E + 255) / 256, 256, 0, stream>>>(eis[r], E, cursor, adjp);
    }

    // ---------- layer 1 (K = 64) ----------
    gather_agg_k<DIN><<<(N_PE + 31) / 32, 256, 0, stream>>>(xh_r, rp[1], adj[1], H1, N_PE);
    gather_agg_k<DIN><<<(N_R + 31) / 32, 256, 0, stream>>>(xh_pe, rp[0], adj[0], H2, N_R);
    gather_agg_k<DIN><<<(N_R + 31) / 32, 256, 0, stream>>>(xh_r, rp[2], adj[2], H3, N_R);
    gemm_mfma_k<2, true><<<gpe, 256, 0, stream>>>(H1, wt_rel1 + 1 * DIN * HID, xh_pe, wt_root1pe,
                                                  nullptr, nullptr, brel1 + HID, nullptr, H4, N_PE, DIN);
    gemm_mfma_k<3, true><<<grr, 256, 0, stream>>>(H2, wt_rel1, H3, wt_rel1 + 2 * DIN * HID, xh_r, wt_wsum1,
                                                  brel1, brel1 + 2 * HID, H5, N_R, DIN);

    // ---------- layer 2 (K = 128), h_pe=H4, h_r=H5 ----------
    gather_agg_k<HID><<<(N_PE + 15) / 16, 256, 0, stream>>>(H5, rp[1], adj[1], H1, N_PE);
    gather_agg_k<HID><<<(N_R + 15) / 16, 256, 0, stream>>>(H4, rp[0], adj[0], H2, N_R);
    gather_agg_k<HID><<<(N_R + 15) / 16, 256, 0, stream>>>(H5, rp[2], adj[2], H3, N_R);
    gemm_mfma_k<2, true><<<gpe, 256, 0, stream>>>(H1, wt_rel23 + 1 * HID * HID, H4, wt_root23 + 1 * HID * HID,
                                                  nullptr, nullptr, brel23 + HID, nullptr, H1, N_PE, HID);
    gemm_mfma_k<3, true><<<grr, 256, 0, stream>>>(H2, wt_rel23, H3, wt_rel23 + 2 * HID * HID, H5, wt_wsum2,
                                                  brel23, brel23 + 2 * HID, H2, N_R, HID);

    // ---------- layer 3 (K = 128), h_pe=H1, h_r=H2, no ReLU ----------
    gather_agg_k<HID><<<(N_PE + 15) / 16, 256, 0, stream>>>(H2, rp[1], adj[1], H3, N_PE);
    gather_agg_k<HID><<<(N_R + 15) / 16, 256, 0, stream>>>(H1, rp[0], adj[0], H4, N_R);
    gather_agg_k<HID><<<(N_R + 15) / 16, 256, 0, stream>>>(H2, rp[2], adj[2], H5, N_R);
    gemm_mfma_k<2, false><<<gpe, 256, 0, stream>>>(H3, wt_rel23 + 4 * HID * HID, H1, wt_root23 + 4 * HID * HID,
                                                   nullptr, nullptr, brel23 + 4 * HID, nullptr, H3, N_PE, HID);
    gemm_mfma_k<3, false><<<grr, 256, 0, stream>>>(H4, wt_rel23 + 3 * HID * HID, H5, wt_rel23 + 5 * HID * HID,
                                                   H2, wt_wsum3, brel23 + 3 * HID, brel23 + 5 * HID, H4, N_R, HID);

    // ---------- readout: segment max + MLP heads ----------
    seg_bounds_k<<<1, 128, 0, stream>>>(batch_pe, N_PE, G, starts_pe);
    seg_bounds_k<<<1, 128, 0, stream>>>(batch_r, N_R, G, starts_r);
    hipMemsetAsync(gmU_pe, 0, 2 * (size_t)G * HID * sizeof(unsigned), stream);
    dim3 gs(G, 16);
    seg_max_k<<<gs, 128, 0, stream>>>(H3, starts_pe, gmU_pe);
    seg_max_k<<<gs, 128, 0, stream>>>(H4, starts_r, gmU_r);
    head_k<<<1, 64, 0, stream>>>(gmU_pe, gmU_r, mlp_W1, mlp_b1, mlp_W2, mlp_b2, out_W, out_b, out, G);
}

// Round 5
// 838.010 us; speedup vs baseline: 10.1518x; 1.1736x over previous
//
#include <hip/hip_runtime.h>
#include <cstddef>
#include <cstdint>

#define DIN 64
#define HID 128

typedef _Float16 half4v __attribute__((ext_vector_type(4)));
typedef _Float16 half8v __attribute__((ext_vector_type(8)));
typedef float f32x16 __attribute__((ext_vector_type(16)));

// ---- order-preserving float<->uint for atomicMax-based segment max ----
__device__ __forceinline__ unsigned encf(float f) {
    unsigned b = __float_as_uint(f);
    return (b & 0x80000000u) ? ~b : (b | 0x80000000u);
}
__device__ __forceinline__ float decf(unsigned u) {
    unsigned b = (u & 0x80000000u) ? (u & 0x7FFFFFFFu) : ~u;
    return __uint_as_float(b);
}

// ---- 3 matrix adds in one launch (Wroot pre-sums), blockIdx.y = job ----
__global__ void matadd3_k(const float* a0, const float* b0f, float* o0, int n0,
                          const float* a1, const float* b1f, float* o1, int n1,
                          const float* a2, const float* b2f, float* o2, int n2) {
    int r = blockIdx.y;
    const float* a = r == 0 ? a0 : (r == 1 ? a1 : a2);
    const float* b = r == 0 ? b0f : (r == 1 ? b1f : b2f);
    float* o = r == 0 ? o0 : (r == 1 ? o1 : o2);
    int n = r == 0 ? n0 : (r == 1 ? n1 : n2);
    int i = blockIdx.x * 256 + threadIdx.x;
    if (i < n) o[i] = a[i] + b[i];
}

// ---- fp32 -> f16 for both inputs in one launch ----
__global__ void conv_x2_k(const float* s0, _Float16* d0, int n40,
                          const float* s1, _Float16* d1, int n41) {
    int r = blockIdx.y;
    const float* s = r == 0 ? s0 : s1;
    _Float16* d = r == 0 ? d0 : d1;
    int n4 = r == 0 ? n40 : n41;
    int i = blockIdx.x * 256 + threadIdx.x;
    if (i >= n4) return;
    float4 v = *reinterpret_cast<const float4*>(&s[i * 4]);
    half4v h;
    h.x = (_Float16)v.x; h.y = (_Float16)v.y; h.z = (_Float16)v.z; h.w = (_Float16)v.w;
    *reinterpret_cast<half4v*>(&d[i * 4]) = h;
}

// ---- 7 weight convert+transpose jobs in one launch; src [M][K][128] -> dst [M][128][K] f16 ----
struct CW { const float* src; _Float16* dst; int K; int total; };
__global__ void conv_w7_k(CW c0, CW c1, CW c2, CW c3, CW c4, CW c5, CW c6) {
    CW J;
    switch (blockIdx.y) {
        case 0: J = c0; break; case 1: J = c1; break; case 2: J = c2; break;
        case 3: J = c3; break; case 4: J = c4; break; case 5: J = c5; break;
        default: J = c6; break;
    }
    int i = blockIdx.x * 256 + threadIdx.x;
    if (i >= J.total) return;
    int m = i / (J.K * HID);
    int rem = i % (J.K * HID);
    int k = rem / HID;
    int col = rem % HID;
    J.dst[(size_t)m * HID * J.K + (size_t)col * J.K + k] = (_Float16)J.src[i];
}

// ================= CSR build, all 3 relations per launch =================
__global__ void zero3_k(int* p0, int n0, int* p1, int n1, int* p2, int n2) {
    int r = blockIdx.y;
    int* p = r == 0 ? p0 : (r == 1 ? p1 : p2);
    int n = r == 0 ? n0 : (r == 1 ? n1 : n2);
    int i = blockIdx.x * 256 + threadIdx.x;
    if (i < n) p[i] = 0;
}

__global__ void hist3_k(const int* e0, const int* e1, const int* e2, int E,
                        int* c0, int* c1, int* c2) {
    int r = blockIdx.y;
    const int* ei = r == 0 ? e0 : (r == 1 ? e1 : e2);
    int* cnt = r == 0 ? c0 : (r == 1 ? c1 : c2);
    int e = blockIdx.x * 256 + threadIdx.x;
    if (e < E) atomicAdd(&cnt[ei[E + e]], 1);
}

__global__ __launch_bounds__(256) void scanA3_k(int* p0, int n0, int* q0,
                                                int* p1, int n1, int* q1,
                                                int* p2, int n2, int* q2) {
    int r = blockIdx.y;
    int* data = r == 0 ? p0 : (r == 1 ? p1 : p2);
    int n = r == 0 ? n0 : (r == 1 ? n1 : n2);
    int* partials = r == 0 ? q0 : (r == 1 ? q1 : q2);
    __shared__ int sh[256];
    int t = threadIdx.x;
    int base = blockIdx.x * 2048 + t * 8;
    int v[8], s = 0;
#pragma unroll
    for (int i = 0; i < 8; ++i) {
        int idx = base + i;
        v[i] = (idx < n) ? data[idx] : 0;
        s += v[i];
    }
    sh[t] = s;
    __syncthreads();
    for (int off = 1; off < 256; off <<= 1) {
        int val = (t >= off) ? sh[t - off] : 0;
        __syncthreads();
        sh[t] += val;
        __syncthreads();
    }
    int run = sh[t] - s;
#pragma unroll
    for (int i = 0; i < 8; ++i) {
        int idx = base + i;
        if (idx < n) data[idx] = run;
        run += v[i];
    }
    if (t == 255) partials[blockIdx.x] = sh[255];
}

__global__ void scanB3_k(int* q0, int* q1, int* q2, int nb) {
    int r = blockIdx.x;
    int* partials = r == 0 ? q0 : (r == 1 ? q1 : q2);
    __shared__ int sh[256];
    int t = threadIdx.x;
    int v = (t < nb) ? partials[t] : 0;
    sh[t] = v;
    __syncthreads();
    for (int off = 1; off < 256; off <<= 1) {
        int val = (t >= off) ? sh[t - off] : 0;
        __syncthreads();
        sh[t] += val;
        __syncthreads();
    }
    if (t < nb) partials[t] = sh[t] - v;
}

__global__ void scanC3_k(int* p0, int n0, const int* q0,
                         int* p1, int n1, const int* q1,
                         int* p2, int n2, const int* q2) {
    int r = blockIdx.y;
    int* data = r == 0 ? p0 : (r == 1 ? p1 : p2);
    int n = r == 0 ? n0 : (r == 1 ? n1 : n2);
    const int* partials = r == 0 ? q0 : (r == 1 ? q1 : q2);
    int i = blockIdx.x * 256 + threadIdx.x;
    if (i < n) data[i] += partials[i >> 11];
}

__global__ void copy3_k(const int* a0, int* b0, int n0,
                        const int* a1, int* b1, int n1,
                        const int* a2, int* b2, int n2) {
    int r = blockIdx.y;
    const int* a = r == 0 ? a0 : (r == 1 ? a1 : a2);
    int* b = r == 0 ? b0 : (r == 1 ? b1 : b2);
    int n = r == 0 ? n0 : (r == 1 ? n1 : n2);
    int i = blockIdx.x * 256 + threadIdx.x;
    if (i < n) b[i] = a[i];
}

__global__ void fill3_k(const int* e0, const int* e1, const int* e2, int E,
                        int* cu0, int* cu1, int* cu2,
                        int* a0, int* a1, int* a2) {
    int r = blockIdx.y;
    const int* ei = r == 0 ? e0 : (r == 1 ? e1 : e2);
    int* cursor = r == 0 ? cu0 : (r == 1 ? cu1 : cu2);
    int* adj = r == 0 ? a0 : (r == 1 ? a1 : a2);
    int e = blockIdx.x * 256 + threadIdx.x;
    if (e < E) {
        int pos = atomicAdd(&cursor[ei[E + e]], 1);
        adj[pos] = ei[e];
    }
}

// ---- 3 gather-sum aggregations in one launch (f16, fp32 accumulate) ----
struct AJob { const _Float16* X; const int* rp; const int* adj; _Float16* AGG; int N; int gb; };
template <int D>
__global__ __launch_bounds__(256) void gather3_k(AJob a0, AJob a1, AJob a2) {
    int b = blockIdx.x;
    AJob J;
    if (b < a0.gb) { J = a0; }
    else if (b < a0.gb + a1.gb) { J = a1; b -= a0.gb; }
    else { J = a2; b -= a0.gb + a1.gb; }
    constexpr int TPN = D / 8;
    constexpr int NPB = 256 / TPN;
    int node = b * NPB + threadIdx.x / TPN;
    int lane = threadIdx.x % TPN;
    if (node >= J.N) return;
    int a = J.rp[node], e1 = J.rp[node + 1];
    float acc[8] = {0.f, 0.f, 0.f, 0.f, 0.f, 0.f, 0.f, 0.f};
    for (int e = a; e < e1; ++e) {
        int s = J.adj[e];
        half8v v = *reinterpret_cast<const half8v*>(&J.X[(size_t)s * D + lane * 8]);
#pragma unroll
        for (int i = 0; i < 8; ++i) acc[i] += (float)v[i];
    }
    half8v o;
#pragma unroll
    for (int i = 0; i < 8; ++i) o[i] = (_Float16)acc[i];
    *reinterpret_cast<half8v*>(&J.AGG[(size_t)node * D + lane * 8]) = o;
}

// ======================= dual-job MFMA GEMM =======================
// Two independent GEMM jobs (pe + router) in one launch for occupancy.
// O[N,128] = sum_s A_s[N,K] @ W_s[K,128] + b0 (+ b1), opt ReLU; f16 act, fp32 acc.
// Double-buffered LDS (1 barrier/chunk) + 2-deep register prefetch.
// Operand-swapped MFMA: D[m=feature][n=node] -> lane owns 16 features of ONE node
// -> coalesced 8 B stores. In-place O==A_s safe: block reads only rows it writes.
struct GJob {
    const _Float16* A0; const _Float16* A1; const _Float16* A2;
    const _Float16* W0; const _Float16* W1; const _Float16* W2;
    const float* b0; const float* b1;
    _Float16* O;
    int N; int total; int gb;   // total = NA * (K/32)
};

template <bool RELU>
__global__ __launch_bounds__(256) void gemm2_k(GJob j0, GJob j1, int K, int lg) {
    const bool second = ((int)blockIdx.x >= j0.gb);
    const GJob J = second ? j1 : j0;
    const int bx = blockIdx.x - (second ? j0.gb : 0);
    __shared__ _Float16 Alds[2][128 * 32];  // 2 x 8 KB
    const int tid = threadIdx.x;
    const int lane = tid & 63;
    const int w = tid >> 6;
    const int wr = w & 1, wc = w >> 1;
    const int rowBase = bx * 128;

    f32x16 acc[2][2];
#pragma unroll
    for (int r = 0; r < 2; ++r)
#pragma unroll
        for (int c = 0; c < 2; ++c)
#pragma unroll
            for (int q = 0; q < 16; ++q) acc[r][c][q] = 0.0f;

    const _Float16* Ap[3] = {J.A0, J.A1, J.A2};

    // staging: lane-consecutive rows -> conflict-free 16 B LDS writes, frag-ready layout
    const int srow = tid & 127;
    const int skh = (tid >> 7) * 16;
    const int gr = rowBase + srow;
    const bool rowOK = (gr < J.N);
    const int sR = (srow >> 5) * 2 + (skh >> 4);
    const int sl5 = srow & 31;
    const int off0 = (sR * 64 + sl5) * 8;
    const int off1 = (sR * 64 + sl5 + 32) * 8;

    const int total = J.total;
    const int cmask = (1 << lg) - 1;

    auto ld = [&](int c, half8v& h0, half8v& h1) {
        int s = c >> lg;
        int k0 = (c & cmask) * 32;
        half8v z = {};
        h0 = z; h1 = z;
        if (rowOK) {
            const _Float16* p = Ap[s] + (size_t)gr * K + k0 + skh;
            h0 = *reinterpret_cast<const half8v*>(p);
            h1 = *reinterpret_cast<const half8v*>(p + 8);
        }
    };

    half8v pa, pb, na, nb, fa, fb;
    ld(0, pa, pb);
    *reinterpret_cast<half8v*>(&Alds[0][off0]) = pa;
    *reinterpret_cast<half8v*>(&Alds[0][off1]) = pb;
    if (total > 1) ld(1, na, nb);
    __syncthreads();

    for (int c = 0; c < total; ++c) {
        if (c + 2 < total) ld(c + 2, fa, fb);
        int s = c >> lg;
        int k0 = (c & cmask) * 32;
        const _Float16* __restrict__ Wt = (s == 0) ? J.W0 : (s == 1 ? J.W1 : J.W2);
        const _Float16* buf = Alds[c & 1];
#pragma unroll
        for (int t = 0; t < 2; ++t) {
            half8v av[2], wv[2];
#pragma unroll
            for (int r = 0; r < 2; ++r) {
                int R = (wr * 2 + r) * 2 + t;
                av[r] = *reinterpret_cast<const half8v*>(&buf[(R * 64 + lane) * 8]);
            }
#pragma unroll
            for (int cc = 0; cc < 2; ++cc) {
                int col = wc * 64 + cc * 32 + (lane & 31);
                wv[cc] = *reinterpret_cast<const half8v*>(
                    &Wt[(size_t)col * K + k0 + t * 16 + (lane >> 5) * 8]);
            }
#pragma unroll
            for (int r = 0; r < 2; ++r)
#pragma unroll
                for (int cc = 0; cc < 2; ++cc)
                    acc[r][cc] = __builtin_amdgcn_mfma_f32_32x32x16_f16(wv[cc], av[r], acc[r][cc], 0, 0, 0);
        }
        if (c + 1 < total) {
            _Float16* nbuf = Alds[(c + 1) & 1];
            *reinterpret_cast<half8v*>(&nbuf[off0]) = na;
            *reinterpret_cast<half8v*>(&nbuf[off1]) = nb;
        }
        __syncthreads();
        na = fa; nb = fb;
    }

    // epilogue: lane owns node = rowBase + tile + (lane&31); 16 features per C-tile.
    // D mapping (swapped): feature-in-tile = (q&3) + 8*(q>>2) + 4*(lane>>5), node = lane&31.
#pragma unroll
    for (int r = 0; r < 2; ++r) {
        int node = rowBase + (wr * 2 + r) * 32 + (lane & 31);
        if (node >= J.N) continue;
        _Float16* orow = J.O + (size_t)node * HID;
#pragma unroll
        for (int cc = 0; cc < 2; ++cc) {
            int fb_ = wc * 64 + cc * 32 + 4 * (lane >> 5);
#pragma unroll
            for (int g = 0; g < 4; ++g) {
                int f = fb_ + g * 8;
                float4 bv = *reinterpret_cast<const float4*>(&J.b0[f]);
                if (J.b1) {
                    float4 b2v = *reinterpret_cast<const float4*>(&J.b1[f]);
                    bv.x += b2v.x; bv.y += b2v.y; bv.z += b2v.z; bv.w += b2v.w;
                }
                half4v hv;
#pragma unroll
                for (int i = 0; i < 4; ++i) {
                    float v = acc[r][cc][g * 4 + i] + ((const float*)&bv)[i];
                    if (RELU) v = fmaxf(v, 0.f);
                    hv[i] = (_Float16)v;
                }
                *reinterpret_cast<half4v*>(&orow[f]) = hv;
            }
        }
    }
}

// ---- segment boundaries for both node types in one launch ----
__global__ void seg_bounds2_k(const int* b0, int n0, int* s0,
                              const int* b1, int n1, int* s1, int G) {
    int r = blockIdx.x;
    const int* batch = r == 0 ? b0 : b1;
    int n = r == 0 ? n0 : n1;
    int* starts = r == 0 ? s0 : s1;
    int g = threadIdx.x;
    if (g > G) return;
    int lo = 0, hi = n;
    while (lo < hi) {
        int mid = (lo + hi) >> 1;
        if (batch[mid] < g) lo = mid + 1; else hi = mid;
    }
    starts[g] = lo;
}

// ---- segment max for both node types: grid (G, SUB, 2) ----
__global__ __launch_bounds__(128) void seg_max2_k(const _Float16* H0, const int* st0, unsigned* g0,
                                                  const _Float16* H1, const int* st1, unsigned* g1) {
    int z = blockIdx.z;
    const _Float16* Hf = z == 0 ? H0 : H1;
    const int* starts = z == 0 ? st0 : st1;
    unsigned* gmU = z == 0 ? g0 : g1;
    int g = blockIdx.x;
    int sub = blockIdx.y;
    int SUB = gridDim.y;
    int f = threadIdx.x;
    int s0 = starts[g], s1 = starts[g + 1];
    int len = s1 - s0;
    if (len <= 0) return;
    int chunk = (len + SUB - 1) / SUB;
    int a = s0 + sub * chunk;
    int b = min(a + chunk, s1);
    if (a >= b) return;
    float m = -__builtin_huge_valf();
    for (int n = a; n < b; ++n) m = fmaxf(m, (float)Hf[(size_t)n * HID + f]);
    atomicMax(&gmU[g * HID + f], encf(m));
}

// ---- per-graph MLP heads + final combine; one thread per graph ----
__global__ void head_k(const unsigned* __restrict__ gmU_pe, const unsigned* __restrict__ gmU_r,
                       const float* __restrict__ W1, const float* __restrict__ b1,
                       const float* __restrict__ W2, const float* __restrict__ b2,
                       const float* __restrict__ oW, const float* __restrict__ ob,
                       float* __restrict__ out, int G) {
    int g = threadIdx.x;
    if (g >= G) return;
    float vals[2];
#pragma unroll
    for (int t = 0; t < 2; ++t) {
        const unsigned* gm = t ? gmU_r : gmU_pe;
        float z[5];
#pragma unroll
        for (int j = 0; j < 5; ++j) z[j] = b1[t * 5 + j];
        for (int f = 0; f < HID; ++f) {
            float x = decf(gm[g * HID + f]);
#pragma unroll
            for (int j = 0; j < 5; ++j) z[j] = fmaf(x, W1[t * HID * 5 + f * 5 + j], z[j]);
        }
        float o = b2[t];
#pragma unroll
        for (int j = 0; j < 5; ++j) o = fmaf(fmaxf(z[j], 0.f), W2[t * 5 + j], o);
        vals[t] = o;
    }
    out[g] = vals[0] * oW[0] + vals[1] * oW[1] + ob[0];
}

extern "C" void kernel_launch(void* const* d_in, const int* in_sizes, int n_in,
                              void* d_out, int out_size, void* d_ws, size_t ws_size,
                              hipStream_t stream) {
    const float* x_pe    = (const float*)d_in[0];
    const float* x_r     = (const float*)d_in[1];
    const int* ei_per    = (const int*)d_in[2];
    const int* ei_rpe    = (const int*)d_in[3];
    const int* ei_rr     = (const int*)d_in[4];
    const int* batch_pe  = (const int*)d_in[5];
    const int* batch_r   = (const int*)d_in[6];
    const float* Wrel1   = (const float*)d_in[7];
    const float* brel1   = (const float*)d_in[8];
    const float* Wroot1  = (const float*)d_in[9];
    const float* Wrel23  = (const float*)d_in[10];
    const float* brel23  = (const float*)d_in[11];
    const float* Wroot23 = (const float*)d_in[12];
    const float* mlp_W1  = (const float*)d_in[13];
    const float* mlp_b1  = (const float*)d_in[14];
    const float* mlp_W2  = (const float*)d_in[15];
    const float* mlp_b2  = (const float*)d_in[16];
    const float* out_W   = (const float*)d_in[17];
    const float* out_b   = (const float*)d_in[18];
    float* out = (float*)d_out;

    const int N_PE = in_sizes[0] / DIN;
    const int N_R  = in_sizes[1] / DIN;
    const int E    = in_sizes[2] / 2;
    const int G    = out_size;
    const int NMAX = (N_PE > N_R) ? N_PE : N_R;
    const size_t SZM = (size_t)NMAX * HID;

    // ---- workspace layout (f16 activations) ----
    _Float16* H1 = (_Float16*)d_ws;
    _Float16* H2 = H1 + SZM;
    _Float16* H3 = H2 + SZM;
    _Float16* H4 = H3 + SZM;
    _Float16* H5 = H4 + SZM;
    _Float16* xh_pe = H5 + SZM;
    _Float16* xh_r  = xh_pe + (size_t)N_PE * DIN;
    float* wsum1 = (float*)(xh_r + (size_t)N_R * DIN);
    float* wsum2 = wsum1 + DIN * HID;
    float* wsum3 = wsum2 + HID * HID;
    _Float16* wt_rel1    = (_Float16*)(wsum3 + HID * HID);  // 3 x 128 x 64
    _Float16* wt_root1pe = wt_rel1 + 3 * DIN * HID;
    _Float16* wt_wsum1   = wt_root1pe + DIN * HID;
    _Float16* wt_rel23   = wt_wsum1 + DIN * HID;            // 6 x 128 x 128
    _Float16* wt_root23  = wt_rel23 + 6 * HID * HID;        // 6 x 128 x 128
    _Float16* wt_wsum2   = wt_root23 + 6 * HID * HID;
    _Float16* wt_wsum3   = wt_wsum2 + HID * HID;
    unsigned* gmU_pe = (unsigned*)(wt_wsum3 + HID * HID);
    unsigned* gmU_r  = gmU_pe + G * HID;
    int* starts_pe = (int*)(gmU_r + G * HID);
    int* starts_r  = starts_pe + (G + 1);
    int* csr = starts_r + (G + 1);
    const size_t relstride = (size_t)(2 * NMAX + E + 65);

    int* rp[3]; int* adjp[3]; int* cur[3]; int* par[3];
    const int Nds[3] = {N_R, N_PE, N_R};
    for (int r = 0; r < 3; ++r) {
        int* rowptr = csr + (size_t)r * relstride;
        rp[r] = rowptr;
        adjp[r] = rowptr + (Nds[r] + 1);
        cur[r] = adjp[r] + E;
        par[r] = cur[r] + Nds[r];
    }

    const int gpe = (N_PE + 127) / 128, grr = (N_R + 127) / 128;

    // ---- pre-sums (1 launch) ----
    {
        dim3 g((16384 + 255) / 256, 3);
        matadd3_k<<<g, 256, 0, stream>>>(
            Wroot1, Wroot1 + 2 * DIN * HID, wsum1, DIN * HID,
            Wroot23, Wroot23 + 2 * HID * HID, wsum2, HID * HID,
            Wroot23 + 3 * HID * HID, Wroot23 + 5 * HID * HID, wsum3, HID * HID);
    }
    // ---- input conversion (1 launch) ----
    {
        int n40 = N_PE * DIN / 4, n41 = N_R * DIN / 4;
        int nmax = n40 > n41 ? n40 : n41;
        dim3 g((nmax + 255) / 256, 2);
        conv_x2_k<<<g, 256, 0, stream>>>(x_pe, xh_pe, n40, x_r, xh_r, n41);
    }
    // ---- weight conversion, 7 jobs (1 launch) ----
    {
        CW c0{Wrel1, wt_rel1, DIN, 3 * DIN * HID};
        CW c1{Wroot1 + 1 * DIN * HID, wt_root1pe, DIN, DIN * HID};
        CW c2{wsum1, wt_wsum1, DIN, DIN * HID};
        CW c3{Wrel23, wt_rel23, HID, 6 * HID * HID};
        CW c4{Wroot23, wt_root23, HID, 6 * HID * HID};
        CW c5{wsum2, wt_wsum2, HID, HID * HID};
        CW c6{wsum3, wt_wsum3, HID, HID * HID};
        dim3 g((6 * HID * HID + 255) / 256, 7);
        conv_w7_k<<<g, 256, 0, stream>>>(c0, c1, c2, c3, c4, c5, c6);
    }
    // ---- CSR build, all relations per launch ----
    {
        dim3 gz((NMAX + 1 + 255) / 256, 3);
        zero3_k<<<gz, 256, 0, stream>>>(rp[0], Nds[0] + 1, rp[1], Nds[1] + 1, rp[2], Nds[2] + 1);
        dim3 ge((E + 255) / 256, 3);
        hist3_k<<<ge, 256, 0, stream>>>(ei_per, ei_rpe, ei_rr, E, rp[0], rp[1], rp[2]);
        int nmax1 = NMAX + 1;
        int nb = (nmax1 + 2047) / 2048;
        dim3 gs(nb, 3);
        scanA3_k<<<gs, 256, 0, stream>>>(rp[0], Nds[0] + 1, par[0],
                                         rp[1], Nds[1] + 1, par[1],
                                         rp[2], Nds[2] + 1, par[2]);
        scanB3_k<<<3, 256, 0, stream>>>(par[0], par[1], par[2], nb);
        dim3 gc(nb * 8, 3);
        scanC3_k<<<gc, 256, 0, stream>>>(rp[0], Nds[0] + 1, par[0],
                                         rp[1], Nds[1] + 1, par[1],
                                         rp[2], Nds[2] + 1, par[2]);
        dim3 gcp((NMAX + 255) / 256, 3);
        copy3_k<<<gcp, 256, 0, stream>>>(rp[0], cur[0], Nds[0],
                                         rp[1], cur[1], Nds[1],
                                         rp[2], cur[2], Nds[2]);
        fill3_k<<<ge, 256, 0, stream>>>(ei_per, ei_rpe, ei_rr, E,
                                        cur[0], cur[1], cur[2],
                                        adjp[0], adjp[1], adjp[2]);
    }

    // ---------- layer 1 (K = 64) ----------
    {
        AJob a0{xh_r, rp[1], adjp[1], H1, N_PE, (N_PE + 31) / 32};
        AJob a1{xh_pe, rp[0], adjp[0], H2, N_R, (N_R + 31) / 32};
        AJob a2{xh_r, rp[2], adjp[2], H3, N_R, (N_R + 31) / 32};
        gather3_k<DIN><<<a0.gb + a1.gb + a2.gb, 256, 0, stream>>>(a0, a1, a2);
        GJob jp{H1, xh_pe, nullptr,
                wt_rel1 + 1 * DIN * HID, wt_root1pe, nullptr,
                brel1 + HID, nullptr, H4, N_PE, 2 * 2, gpe};
        GJob jr{H2, H3, xh_r,
                wt_rel1, wt_rel1 + 2 * DIN * HID, wt_wsum1,
                brel1, brel1 + 2 * HID, H5, N_R, 3 * 2, grr};
        gemm2_k<true><<<gpe + grr, 256, 0, stream>>>(jp, jr, DIN, 1);
    }
    // ---------- layer 2 (K = 128), h_pe=H4, h_r=H5 ----------
    {
        AJob a0{H5, rp[1], adjp[1], H1, N_PE, (N_PE + 15) / 16};
        AJob a1{H4, rp[0], adjp[0], H2, N_R, (N_R + 15) / 16};
        AJob a2{H5, rp[2], adjp[2], H3, N_R, (N_R + 15) / 16};
        gather3_k<HID><<<a0.gb + a1.gb + a2.gb, 256, 0, stream>>>(a0, a1, a2);
        GJob jp{H1, H4, nullptr,
                wt_rel23 + 1 * HID * HID, wt_root23 + 1 * HID * HID, nullptr,
                brel23 + HID, nullptr, H1, N_PE, 2 * 4, gpe};
        GJob jr{H2, H3, H5,
                wt_rel23, wt_rel23 + 2 * HID * HID, wt_wsum2,
                brel23, brel23 + 2 * HID, H2, N_R, 3 * 4, grr};
        gemm2_k<true><<<gpe + grr, 256, 0, stream>>>(jp, jr, HID, 2);
    }
    // ---------- layer 3 (K = 128), h_pe=H1, h_r=H2, no ReLU ----------
    {
        AJob a0{H2, rp[1], adjp[1], H3, N_PE, (N_PE + 15) / 16};
        AJob a1{H1, rp[0], adjp[0], H4, N_R, (N_R + 15) / 16};
        AJob a2{H2, rp[2], adjp[2], H5, N_R, (N_R + 15) / 16};
        gather3_k<HID><<<a0.gb + a1.gb + a2.gb, 256, 0, stream>>>(a0, a1, a2);
        GJob jp{H3, H1, nullptr,
                wt_rel23 + 4 * HID * HID, wt_root23 + 4 * HID * HID, nullptr,
                brel23 + 4 * HID, nullptr, H3, N_PE, 2 * 4, gpe};
        GJob jr{H4, H5, H2,
                wt_rel23 + 3 * HID * HID, wt_rel23 + 5 * HID * HID, wt_wsum3,
                brel23 + 3 * HID, brel23 + 5 * HID, H4, N_R, 3 * 4, grr};
        gemm2_k<false><<<gpe + grr, 256, 0, stream>>>(jp, jr, HID, 2);
    }

    // ---------- readout ----------
    seg_bounds2_k<<<2, 128, 0, stream>>>(batch_pe, N_PE, starts_pe, batch_r, N_R, starts_r, G);
    hipMemsetAsync(gmU_pe, 0, 2 * (size_t)G * HID * sizeof(unsigned), stream);
    dim3 gs(G, 16, 2);
    seg_max2_k<<<gs, 128, 0, stream>>>(H3, starts_pe, gmU_pe, H4, starts_r, gmU_r);
    head_k<<<1, 64, 0, stream>>>(gmU_pe, gmU_r, mlp_W1, mlp_b1, mlp_W2, mlp_b2, out_W, out_b, out, G);
}

// Round 6
// 643.244 us; speedup vs baseline: 13.2256x; 1.3028x over previous
//
#include <hip/hip_runtime.h>
#include <cstddef>
#include <cstdint>

#define DIN 64
#define HID 128
#define NBKMAX 256   // max dst buckets of 512 nodes -> supports N <= 131072
#define EPB 8192     // edges per bin-pass block

typedef _Float16 half4v __attribute__((ext_vector_type(4)));
typedef _Float16 half8v __attribute__((ext_vector_type(8)));
typedef float f32x16 __attribute__((ext_vector_type(16)));

// ---- order-preserving float<->uint for atomicMax-based segment max ----
__device__ __forceinline__ unsigned encf(float f) {
    unsigned b = __float_as_uint(f);
    return (b & 0x80000000u) ? ~b : (b | 0x80000000u);
}
__device__ __forceinline__ float decf(unsigned u) {
    unsigned b = (u & 0x80000000u) ? (u & 0x7FFFFFFFu) : ~u;
    return __uint_as_float(b);
}

// ---- 3 matrix adds in one launch (Wroot pre-sums) ----
__global__ void matadd3_k(const float* a0, const float* b0f, float* o0, int n0,
                          const float* a1, const float* b1f, float* o1, int n1,
                          const float* a2, const float* b2f, float* o2, int n2) {
    int r = blockIdx.y;
    const float* a = r == 0 ? a0 : (r == 1 ? a1 : a2);
    const float* b = r == 0 ? b0f : (r == 1 ? b1f : b2f);
    float* o = r == 0 ? o0 : (r == 1 ? o1 : o2);
    int n = r == 0 ? n0 : (r == 1 ? n1 : n2);
    int i = blockIdx.x * 256 + threadIdx.x;
    if (i < n) o[i] = a[i] + b[i];
}

// ---- fp32 -> f16 for both inputs in one launch ----
__global__ void conv_x2_k(const float* s0, _Float16* d0, int n40,
                          const float* s1, _Float16* d1, int n41) {
    int r = blockIdx.y;
    const float* s = r == 0 ? s0 : s1;
    _Float16* d = r == 0 ? d0 : d1;
    int n4 = r == 0 ? n40 : n41;
    int i = blockIdx.x * 256 + threadIdx.x;
    if (i >= n4) return;
    float4 v = *reinterpret_cast<const float4*>(&s[i * 4]);
    half4v h;
    h.x = (_Float16)v.x; h.y = (_Float16)v.y; h.z = (_Float16)v.z; h.w = (_Float16)v.w;
    *reinterpret_cast<half4v*>(&d[i * 4]) = h;
}

// ---- 7 weight convert+transpose jobs in one launch ----
struct CW { const float* src; _Float16* dst; int K; int total; };
__global__ void conv_w7_k(CW c0, CW c1, CW c2, CW c3, CW c4, CW c5, CW c6) {
    CW J;
    switch (blockIdx.y) {
        case 0: J = c0; break; case 1: J = c1; break; case 2: J = c2; break;
        case 3: J = c3; break; case 4: J = c4; break; case 5: J = c5; break;
        default: J = c6; break;
    }
    int i = blockIdx.x * 256 + threadIdx.x;
    if (i >= J.total) return;
    int m = i / (J.K * HID);
    int rem = i % (J.K * HID);
    int k = rem / HID;
    int col = rem % HID;
    J.dst[(size_t)m * HID * J.K + (size_t)col * J.K + k] = (_Float16)J.src[i];
}

// ================= CSR build via cache-local counting sort =================
// Phase A0: bucket (dst>>9) histogram. LDS-local then 1 global atomic/bucket/block.
__global__ __launch_bounds__(256) void bhist_k(const int* e0, const int* e1, const int* e2, int E,
                                               int* c0, int* c1, int* c2) {
    int r = blockIdx.y;
    const int* ei = r == 0 ? e0 : (r == 1 ? e1 : e2);
    int* cnt = r == 0 ? c0 : (r == 1 ? c1 : c2);
    __shared__ int sc[NBKMAX];
    int t = threadIdx.x;
    sc[t] = 0;
    __syncthreads();
    int base = blockIdx.x * EPB;
    int n = min(EPB, E - base);
    for (int i = t; i < n; i += 256)
        atomicAdd(&sc[(unsigned)ei[E + base + i] >> 9], 1);
    __syncthreads();
    if (sc[t]) atomicAdd(&cnt[t], sc[t]);
}

// Phase A1: exclusive scan of bucket counts -> bucketBase & cursors; rowptr[N]=E.
__global__ __launch_bounds__(256) void bscan_k(int* c0, int* bb0, int* cu0, int* rp0, int n0,
                                               int* c1, int* bb1, int* cu1, int* rp1, int n1,
                                               int* c2, int* bb2, int* cu2, int* rp2, int n2,
                                               int E) {
    __shared__ int sh[256];
    int t = threadIdx.x;
    for (int r = 0; r < 3; ++r) {
        int* cnt = r == 0 ? c0 : (r == 1 ? c1 : c2);
        int* bb  = r == 0 ? bb0 : (r == 1 ? bb1 : bb2);
        int* cu  = r == 0 ? cu0 : (r == 1 ? cu1 : cu2);
        int* rp  = r == 0 ? rp0 : (r == 1 ? rp1 : rp2);
        int N    = r == 0 ? n0 : (r == 1 ? n1 : n2);
        int v = cnt[t];
        sh[t] = v;
        __syncthreads();
        for (int off = 1; off < 256; off <<= 1) {
            int val = (t >= off) ? sh[t - off] : 0;
            __syncthreads();
            sh[t] += val;
            __syncthreads();
        }
        int ex = sh[t] - v;
        bb[t] = ex;
        cu[t] = ex;
        if (t == 255) bb[256] = sh[255];
        if (t == 0) rp[N] = E;
        __syncthreads();
    }
}

// Phase A2: bin edges into bucket-contiguous temp (packed (src<<9)|dst_local).
__global__ __launch_bounds__(256) void bin_k(const int* e0, const int* e1, const int* e2, int E,
                                             int* cu0, int* cu1, int* cu2,
                                             unsigned* t0, unsigned* t1, unsigned* t2) {
    int r = blockIdx.y;
    const int* ei = r == 0 ? e0 : (r == 1 ? e1 : e2);
    int* gcur = r == 0 ? cu0 : (r == 1 ? cu1 : cu2);
    unsigned* temp = r == 0 ? t0 : (r == 1 ? t1 : t2);
    __shared__ unsigned pk[EPB];
    __shared__ unsigned short bkb[EPB];
    __shared__ int cnt[NBKMAX];
    __shared__ int scn[NBKMAX];
    __shared__ int rb[NBKMAX];
    int t = threadIdx.x;
    int base = blockIdx.x * EPB;
    int n = min(EPB, E - base);
    cnt[t] = 0;
    __syncthreads();
    for (int i = t; i < n; i += 256)
        atomicAdd(&cnt[(unsigned)ei[E + base + i] >> 9], 1);
    __syncthreads();
    // exclusive scan cnt -> scn
    {
        int v = cnt[t];
        scn[t] = v;
        __syncthreads();
        for (int off = 1; off < 256; off <<= 1) {
            int val = (t >= off) ? scn[t - off] : 0;
            __syncthreads();
            scn[t] += val;
            __syncthreads();
        }
        int ex = scn[t] - v;
        __syncthreads();
        scn[t] = ex;
    }
    // global run bases; reset cnt as local cursor
    {
        int c = cnt[t];
        rb[t] = c ? atomicAdd(&gcur[t], c) : 0;
        cnt[t] = 0;
    }
    __syncthreads();
    // place edges into LDS, sorted by bucket
    for (int i = t; i < n; i += 256) {
        int s = ei[base + i];
        int d = ei[E + base + i];
        int b = (unsigned)d >> 9;
        int slot = scn[b] + atomicAdd(&cnt[b], 1);
        pk[slot] = ((unsigned)s << 9) | (unsigned)(d & 511);
        bkb[slot] = (unsigned short)b;
    }
    __syncthreads();
    // flush contiguous runs
    for (int i = t; i < n; i += 256) {
        int b = bkb[i];
        temp[rb[b] + (i - scn[b])] = pk[i];
    }
}

// Phase B: per-bucket exact CSR. All scatters land in an L2-resident window.
__global__ __launch_bounds__(256) void bcsr_k(const unsigned* t0, const unsigned* t1, const unsigned* t2,
                                              const int* bb0, const int* bb1, const int* bb2,
                                              int* rp0, int* rp1, int* rp2,
                                              int* a0, int* a1, int* a2,
                                              int n0, int n1, int n2) {
    int r = blockIdx.y;
    const unsigned* temp = r == 0 ? t0 : (r == 1 ? t1 : t2);
    const int* bb = r == 0 ? bb0 : (r == 1 ? bb1 : bb2);
    int* rp = r == 0 ? rp0 : (r == 1 ? rp1 : rp2);
    int* adj = r == 0 ? a0 : (r == 1 ? a1 : a2);
    int N = r == 0 ? n0 : (r == 1 ? n1 : n2);
    int b = blockIdx.x;
    int lo = bb[b], hi = bb[b + 1];
    __shared__ int cnt[512];
    __shared__ int sh[256];
    int t = threadIdx.x;
    cnt[t] = 0; cnt[t + 256] = 0;
    __syncthreads();
    for (int i = lo + t; i < hi; i += 256)
        atomicAdd(&cnt[temp[i] & 511], 1);
    __syncthreads();
    int c0 = cnt[2 * t], c1 = cnt[2 * t + 1];
    sh[t] = c0 + c1;
    __syncthreads();
    for (int off = 1; off < 256; off <<= 1) {
        int v = (t >= off) ? sh[t - off] : 0;
        __syncthreads();
        sh[t] += v;
        __syncthreads();
    }
    int pairExcl = sh[t] - (c0 + c1);
    __syncthreads();
    int e0x = lo + pairExcl;
    int e1x = e0x + c0;
    cnt[2 * t] = e0x;
    cnt[2 * t + 1] = e1x;
    int nodeBase = b * 512;
    if (nodeBase + 2 * t < N) rp[nodeBase + 2 * t] = e0x;
    if (nodeBase + 2 * t + 1 < N) rp[nodeBase + 2 * t + 1] = e1x;
    __syncthreads();
    for (int i = lo + t; i < hi; i += 256) {
        unsigned p = temp[i];
        int pos = atomicAdd(&cnt[p & 511], 1);
        adj[pos] = p >> 9;
    }
}

// ---- 3 gather-sum aggregations in one launch (f16, fp32 acc, 2-deep MLP) ----
struct AJob { const _Float16* X; const int* rp; const int* adj; _Float16* AGG; int N; int gb; };
template <int D>
__global__ __launch_bounds__(256) void gather3_k(AJob a0, AJob a1, AJob a2) {
    int b = blockIdx.x;
    AJob J;
    if (b < a0.gb) { J = a0; }
    else if (b < a0.gb + a1.gb) { J = a1; b -= a0.gb; }
    else { J = a2; b -= a0.gb + a1.gb; }
    constexpr int TPN = D / 8;
    constexpr int NPB = 256 / TPN;
    int node = b * NPB + threadIdx.x / TPN;
    int lane = threadIdx.x % TPN;
    if (node >= J.N) return;
    int a = J.rp[node], e1 = J.rp[node + 1];
    float acc[8] = {0.f, 0.f, 0.f, 0.f, 0.f, 0.f, 0.f, 0.f};
    int e = a;
    for (; e + 2 <= e1; e += 2) {
        int s0 = J.adj[e], s1 = J.adj[e + 1];
        half8v v0 = *reinterpret_cast<const half8v*>(&J.X[(size_t)s0 * D + lane * 8]);
        half8v v1 = *reinterpret_cast<const half8v*>(&J.X[(size_t)s1 * D + lane * 8]);
#pragma unroll
        for (int i = 0; i < 8; ++i) acc[i] += (float)v0[i];
#pragma unroll
        for (int i = 0; i < 8; ++i) acc[i] += (float)v1[i];
    }
    if (e < e1) {
        int s0 = J.adj[e];
        half8v v0 = *reinterpret_cast<const half8v*>(&J.X[(size_t)s0 * D + lane * 8]);
#pragma unroll
        for (int i = 0; i < 8; ++i) acc[i] += (float)v0[i];
    }
    half8v o;
#pragma unroll
    for (int i = 0; i < 8; ++i) o[i] = (_Float16)acc[i];
    *reinterpret_cast<half8v*>(&J.AGG[(size_t)node * D + lane * 8]) = o;
}

// ======================= dual-job MFMA GEMM (unchanged core) =======================
struct GJob {
    const _Float16* A0; const _Float16* A1; const _Float16* A2;
    const _Float16* W0; const _Float16* W1; const _Float16* W2;
    const float* b0; const float* b1;
    _Float16* O;
    int N; int total; int gb;
};

template <bool RELU>
__global__ __launch_bounds__(256) void gemm2_k(GJob j0, GJob j1, int K, int lg) {
    const bool second = ((int)blockIdx.x >= j0.gb);
    const GJob J = second ? j1 : j0;
    const int bx = blockIdx.x - (second ? j0.gb : 0);
    __shared__ _Float16 Alds[2][128 * 32];
    const int tid = threadIdx.x;
    const int lane = tid & 63;
    const int w = tid >> 6;
    const int wr = w & 1, wc = w >> 1;
    const int rowBase = bx * 128;

    f32x16 acc[2][2];
#pragma unroll
    for (int r = 0; r < 2; ++r)
#pragma unroll
        for (int c = 0; c < 2; ++c)
#pragma unroll
            for (int q = 0; q < 16; ++q) acc[r][c][q] = 0.0f;

    const _Float16* Ap[3] = {J.A0, J.A1, J.A2};

    const int srow = tid & 127;
    const int skh = (tid >> 7) * 16;
    const int gr = rowBase + srow;
    const bool rowOK = (gr < J.N);
    const int sR = (srow >> 5) * 2 + (skh >> 4);
    const int sl5 = srow & 31;
    const int off0 = (sR * 64 + sl5) * 8;
    const int off1 = (sR * 64 + sl5 + 32) * 8;

    const int total = J.total;
    const int cmask = (1 << lg) - 1;

    auto ld = [&](int c, half8v& h0, half8v& h1) {
        int s = c >> lg;
        int k0 = (c & cmask) * 32;
        half8v z = {};
        h0 = z; h1 = z;
        if (rowOK) {
            const _Float16* p = Ap[s] + (size_t)gr * K + k0 + skh;
            h0 = *reinterpret_cast<const half8v*>(p);
            h1 = *reinterpret_cast<const half8v*>(p + 8);
        }
    };

    half8v pa, pb, na, nb, fa, fb;
    ld(0, pa, pb);
    *reinterpret_cast<half8v*>(&Alds[0][off0]) = pa;
    *reinterpret_cast<half8v*>(&Alds[0][off1]) = pb;
    if (total > 1) ld(1, na, nb);
    __syncthreads();

    for (int c = 0; c < total; ++c) {
        if (c + 2 < total) ld(c + 2, fa, fb);
        int s = c >> lg;
        int k0 = (c & cmask) * 32;
        const _Float16* __restrict__ Wt = (s == 0) ? J.W0 : (s == 1 ? J.W1 : J.W2);
        const _Float16* buf = Alds[c & 1];
#pragma unroll
        for (int t = 0; t < 2; ++t) {
            half8v av[2], wv[2];
#pragma unroll
            for (int r = 0; r < 2; ++r) {
                int R = (wr * 2 + r) * 2 + t;
                av[r] = *reinterpret_cast<const half8v*>(&buf[(R * 64 + lane) * 8]);
            }
#pragma unroll
            for (int cc = 0; cc < 2; ++cc) {
                int col = wc * 64 + cc * 32 + (lane & 31);
                wv[cc] = *reinterpret_cast<const half8v*>(
                    &Wt[(size_t)col * K + k0 + t * 16 + (lane >> 5) * 8]);
            }
#pragma unroll
            for (int r = 0; r < 2; ++r)
#pragma unroll
                for (int cc = 0; cc < 2; ++cc)
                    acc[r][cc] = __builtin_amdgcn_mfma_f32_32x32x16_f16(wv[cc], av[r], acc[r][cc], 0, 0, 0);
        }
        if (c + 1 < total) {
            _Float16* nbuf = Alds[(c + 1) & 1];
            *reinterpret_cast<half8v*>(&nbuf[off0]) = na;
            *reinterpret_cast<half8v*>(&nbuf[off1]) = nb;
        }
        __syncthreads();
        na = fa; nb = fb;
    }

#pragma unroll
    for (int r = 0; r < 2; ++r) {
        int node = rowBase + (wr * 2 + r) * 32 + (lane & 31);
        if (node >= J.N) continue;
        _Float16* orow = J.O + (size_t)node * HID;
#pragma unroll
        for (int cc = 0; cc < 2; ++cc) {
            int fb_ = wc * 64 + cc * 32 + 4 * (lane >> 5);
#pragma unroll
            for (int g = 0; g < 4; ++g) {
                int f = fb_ + g * 8;
                float4 bv = *reinterpret_cast<const float4*>(&J.b0[f]);
                if (J.b1) {
                    float4 b2v = *reinterpret_cast<const float4*>(&J.b1[f]);
                    bv.x += b2v.x; bv.y += b2v.y; bv.z += b2v.z; bv.w += b2v.w;
                }
                half4v hv;
#pragma unroll
                for (int i = 0; i < 4; ++i) {
                    float v = acc[r][cc][g * 4 + i] + ((const float*)&bv)[i];
                    if (RELU) v = fmaxf(v, 0.f);
                    hv[i] = (_Float16)v;
                }
                *reinterpret_cast<half4v*>(&orow[f]) = hv;
            }
        }
    }
}

// ---- segment boundaries for both node types ----
__global__ void seg_bounds2_k(const int* b0, int n0, int* s0,
                              const int* b1, int n1, int* s1, int G) {
    int r = blockIdx.x;
    const int* batch = r == 0 ? b0 : b1;
    int n = r == 0 ? n0 : n1;
    int* starts = r == 0 ? s0 : s1;
    int g = threadIdx.x;
    if (g > G) return;
    int lo = 0, hi = n;
    while (lo < hi) {
        int mid = (lo + hi) >> 1;
        if (batch[mid] < g) lo = mid + 1; else hi = mid;
    }
    starts[g] = lo;
}

// ---- segment max for both node types: grid (G, SUB, 2) ----
__global__ __launch_bounds__(128) void seg_max2_k(const _Float16* H0, const int* st0, unsigned* g0,
                                                  const _Float16* H1, const int* st1, unsigned* g1) {
    int z = blockIdx.z;
    const _Float16* Hf = z == 0 ? H0 : H1;
    const int* starts = z == 0 ? st0 : st1;
    unsigned* gmU = z == 0 ? g0 : g1;
    int g = blockIdx.x;
    int sub = blockIdx.y;
    int SUB = gridDim.y;
    int f = threadIdx.x;
    int s0 = starts[g], s1 = starts[g + 1];
    int len = s1 - s0;
    if (len <= 0) return;
    int chunk = (len + SUB - 1) / SUB;
    int a = s0 + sub * chunk;
    int b = min(a + chunk, s1);
    if (a >= b) return;
    float m = -__builtin_huge_valf();
    for (int n = a; n < b; ++n) m = fmaxf(m, (float)Hf[(size_t)n * HID + f]);
    atomicMax(&gmU[g * HID + f], encf(m));
}

// ---- per-graph MLP heads + final combine ----
__global__ void head_k(const unsigned* __restrict__ gmU_pe, const unsigned* __restrict__ gmU_r,
                       const float* __restrict__ W1, const float* __restrict__ b1,
                       const float* __restrict__ W2, const float* __restrict__ b2,
                       const float* __restrict__ oW, const float* __restrict__ ob,
                       float* __restrict__ out, int G) {
    int g = threadIdx.x;
    if (g >= G) return;
    float vals[2];
#pragma unroll
    for (int t = 0; t < 2; ++t) {
        const unsigned* gm = t ? gmU_r : gmU_pe;
        float z[5];
#pragma unroll
        for (int j = 0; j < 5; ++j) z[j] = b1[t * 5 + j];
        for (int f = 0; f < HID; ++f) {
            float x = decf(gm[g * HID + f]);
#pragma unroll
            for (int j = 0; j < 5; ++j) z[j] = fmaf(x, W1[t * HID * 5 + f * 5 + j], z[j]);
        }
        float o = b2[t];
#pragma unroll
        for (int j = 0; j < 5; ++j) o = fmaf(fmaxf(z[j], 0.f), W2[t * 5 + j], o);
        vals[t] = o;
    }
    out[g] = vals[0] * oW[0] + vals[1] * oW[1] + ob[0];
}

extern "C" void kernel_launch(void* const* d_in, const int* in_sizes, int n_in,
                              void* d_out, int out_size, void* d_ws, size_t ws_size,
                              hipStream_t stream) {
    const float* x_pe    = (const float*)d_in[0];
    const float* x_r     = (const float*)d_in[1];
    const int* ei_per    = (const int*)d_in[2];
    const int* ei_rpe    = (const int*)d_in[3];
    const int* ei_rr     = (const int*)d_in[4];
    const int* batch_pe  = (const int*)d_in[5];
    const int* batch_r   = (const int*)d_in[6];
    const float* Wrel1   = (const float*)d_in[7];
    const float* brel1   = (const float*)d_in[8];
    const float* Wroot1  = (const float*)d_in[9];
    const float* Wrel23  = (const float*)d_in[10];
    const float* brel23  = (const float*)d_in[11];
    const float* Wroot23 = (const float*)d_in[12];
    const float* mlp_W1  = (const float*)d_in[13];
    const float* mlp_b1  = (const float*)d_in[14];
    const float* mlp_W2  = (const float*)d_in[15];
    const float* mlp_b2  = (const float*)d_in[16];
    const float* out_W   = (const float*)d_in[17];
    const float* out_b   = (const float*)d_in[18];
    float* out = (float*)d_out;

    const int N_PE = in_sizes[0] / DIN;
    const int N_R  = in_sizes[1] / DIN;
    const int E    = in_sizes[2] / 2;
    const int G    = out_size;
    const int NMAX = (N_PE > N_R) ? N_PE : N_R;
    const size_t SZM = (size_t)NMAX * HID;

    // ---- workspace layout ----
    _Float16* H1 = (_Float16*)d_ws;
    _Float16* H2 = H1 + SZM;
    _Float16* H3 = H2 + SZM;
    _Float16* H4 = H3 + SZM;
    _Float16* H5 = H4 + SZM;
    _Float16* xh_pe = H5 + SZM;
    _Float16* xh_r  = xh_pe + (size_t)N_PE * DIN;
    float* wsum1 = (float*)(xh_r + (size_t)N_R * DIN);
    float* wsum2 = wsum1 + DIN * HID;
    float* wsum3 = wsum2 + HID * HID;
    _Float16* wt_rel1    = (_Float16*)(wsum3 + HID * HID);
    _Float16* wt_root1pe = wt_rel1 + 3 * DIN * HID;
    _Float16* wt_wsum1   = wt_root1pe + DIN * HID;
    _Float16* wt_rel23   = wt_wsum1 + DIN * HID;
    _Float16* wt_root23  = wt_rel23 + 6 * HID * HID;
    _Float16* wt_wsum2   = wt_root23 + 6 * HID * HID;
    _Float16* wt_wsum3   = wt_wsum2 + HID * HID;
    unsigned* gmU_pe = (unsigned*)(wt_wsum3 + HID * HID);
    unsigned* gmU_r  = gmU_pe + G * HID;
    int* starts_pe = (int*)(gmU_r + G * HID);
    int* starts_r  = starts_pe + (G + 1);
    // bucket arrays (contiguous for one memset)
    int* bktCnt = starts_r + (G + 1);            // 3 * NBKMAX
    int* bb     = bktCnt + 3 * NBKMAX;           // 3 * (NBKMAX+1)
    int* gcur   = bb + 3 * (NBKMAX + 1);         // 3 * NBKMAX
    int* csr    = gcur + 3 * NBKMAX;
    const size_t relstride = (size_t)(NMAX + 1) + 2 * (size_t)E + 16;

    int* rp[3]; int* adjp[3]; unsigned* tmp[3];
    const int Nds[3] = {N_R, N_PE, N_R};
    for (int r = 0; r < 3; ++r) {
        int* rowptr = csr + (size_t)r * relstride;
        rp[r] = rowptr;
        adjp[r] = rowptr + (Nds[r] + 1);
        tmp[r] = (unsigned*)(adjp[r] + E);
    }

    const int gpe = (N_PE + 127) / 128, grr = (N_R + 127) / 128;

    // ---- pre-sums ----
    {
        dim3 g((16384 + 255) / 256, 3);
        matadd3_k<<<g, 256, 0, stream>>>(
            Wroot1, Wroot1 + 2 * DIN * HID, wsum1, DIN * HID,
            Wroot23, Wroot23 + 2 * HID * HID, wsum2, HID * HID,
            Wroot23 + 3 * HID * HID, Wroot23 + 5 * HID * HID, wsum3, HID * HID);
    }
    // ---- input conversion ----
    {
        int n40 = N_PE * DIN / 4, n41 = N_R * DIN / 4;
        int nmax = n40 > n41 ? n40 : n41;
        dim3 g((nmax + 255) / 256, 2);
        conv_x2_k<<<g, 256, 0, stream>>>(x_pe, xh_pe, n40, x_r, xh_r, n41);
    }
    // ---- weight conversion ----
    {
        CW c0{Wrel1, wt_rel1, DIN, 3 * DIN * HID};
        CW c1{Wroot1 + 1 * DIN * HID, wt_root1pe, DIN, DIN * HID};
        CW c2{wsum1, wt_wsum1, DIN, DIN * HID};
        CW c3{Wrel23, wt_rel23, HID, 6 * HID * HID};
        CW c4{Wroot23, wt_root23, HID, 6 * HID * HID};
        CW c5{wsum2, wt_wsum2, HID, HID * HID};
        CW c6{wsum3, wt_wsum3, HID, HID * HID};
        dim3 g((6 * HID * HID + 255) / 256, 7);
        conv_w7_k<<<g, 256, 0, stream>>>(c0, c1, c2, c3, c4, c5, c6);
    }
    // ---- CSR build: bucketed counting sort ----
    {
        hipMemsetAsync(bktCnt, 0, 3 * NBKMAX * sizeof(int), stream);
        int eb = (E + EPB - 1) / EPB;
        dim3 gh(eb, 3);
        bhist_k<<<gh, 256, 0, stream>>>(ei_per, ei_rpe, ei_rr, E,
                                        bktCnt, bktCnt + NBKMAX, bktCnt + 2 * NBKMAX);
        bscan_k<<<1, 256, 0, stream>>>(
            bktCnt, bb, gcur, rp[0], Nds[0],
            bktCnt + NBKMAX, bb + (NBKMAX + 1), gcur + NBKMAX, rp[1], Nds[1],
            bktCnt + 2 * NBKMAX, bb + 2 * (NBKMAX + 1), gcur + 2 * NBKMAX, rp[2], Nds[2], E);
        bin_k<<<gh, 256, 0, stream>>>(ei_per, ei_rpe, ei_rr, E,
                                      gcur, gcur + NBKMAX, gcur + 2 * NBKMAX,
                                      tmp[0], tmp[1], tmp[2]);
        dim3 gc(NBKMAX, 3);
        bcsr_k<<<gc, 256, 0, stream>>>(tmp[0], tmp[1], tmp[2],
                                       bb, bb + (NBKMAX + 1), bb + 2 * (NBKMAX + 1),
                                       rp[0], rp[1], rp[2],
                                       adjp[0], adjp[1], adjp[2],
                                       Nds[0], Nds[1], Nds[2]);
    }

    // ---------- layer 1 (K = 64) ----------
    {
        AJob a0{xh_r, rp[1], adjp[1], H1, N_PE, (N_PE + 31) / 32};
        AJob a1{xh_pe, rp[0], adjp[0], H2, N_R, (N_R + 31) / 32};
        AJob a2{xh_r, rp[2], adjp[2], H3, N_R, (N_R + 31) / 32};
        gather3_k<DIN><<<a0.gb + a1.gb + a2.gb, 256, 0, stream>>>(a0, a1, a2);
        GJob jp{H1, xh_pe, nullptr,
                wt_rel1 + 1 * DIN * HID, wt_root1pe, nullptr,
                brel1 + HID, nullptr, H4, N_PE, 2 * 2, gpe};
        GJob jr{H2, H3, xh_r,
                wt_rel1, wt_rel1 + 2 * DIN * HID, wt_wsum1,
                brel1, brel1 + 2 * HID, H5, N_R, 3 * 2, grr};
        gemm2_k<true><<<gpe + grr, 256, 0, stream>>>(jp, jr, DIN, 1);
    }
    // ---------- layer 2 (K = 128) ----------
    {
        AJob a0{H5, rp[1], adjp[1], H1, N_PE, (N_PE + 15) / 16};
        AJob a1{H4, rp[0], adjp[0], H2, N_R, (N_R + 15) / 16};
        AJob a2{H5, rp[2], adjp[2], H3, N_R, (N_R + 15) / 16};
        gather3_k<HID><<<a0.gb + a1.gb + a2.gb, 256, 0, stream>>>(a0, a1, a2);
        GJob jp{H1, H4, nullptr,
                wt_rel23 + 1 * HID * HID, wt_root23 + 1 * HID * HID, nullptr,
                brel23 + HID, nullptr, H1, N_PE, 2 * 4, gpe};
        GJob jr{H2, H3, H5,
                wt_rel23, wt_rel23 + 2 * HID * HID, wt_wsum2,
                brel23, brel23 + 2 * HID, H2, N_R, 3 * 4, grr};
        gemm2_k<true><<<gpe + grr, 256, 0, stream>>>(jp, jr, HID, 2);
    }
    // ---------- layer 3 (K = 128), no ReLU ----------
    {
        AJob a0{H2, rp[1], adjp[1], H3, N_PE, (N_PE + 15) / 16};
        AJob a1{H1, rp[0], adjp[0], H4, N_R, (N_R + 15) / 16};
        AJob a2{H2, rp[2], adjp[2], H5, N_R, (N_R + 15) / 16};
        gather3_k<HID><<<a0.gb + a1.gb + a2.gb, 256, 0, stream>>>(a0, a1, a2);
        GJob jp{H3, H1, nullptr,
                wt_rel23 + 4 * HID * HID, wt_root23 + 4 * HID * HID, nullptr,
                brel23 + 4 * HID, nullptr, H3, N_PE, 2 * 4, gpe};
        GJob jr{H4, H5, H2,
                wt_rel23 + 3 * HID * HID, wt_rel23 + 5 * HID * HID, wt_wsum3,
                brel23 + 3 * HID, brel23 + 5 * HID, H4, N_R, 3 * 4, grr};
        gemm2_k<false><<<gpe + grr, 256, 0, stream>>>(jp, jr, HID, 2);
    }

    // ---------- readout ----------
    seg_bounds2_k<<<2, 128, 0, stream>>>(batch_pe, N_PE, starts_pe, batch_r, N_R, starts_r, G);
    hipMemsetAsync(gmU_pe, 0, 2 * (size_t)G * HID * sizeof(unsigned), stream);
    dim3 gs(G, 16, 2);
    seg_max2_k<<<gs, 128, 0, stream>>>(H3, starts_pe, gmU_pe, H4, starts_r, gmU_r);
    head_k<<<1, 64, 0, stream>>>(gmU_pe, gmU_r, mlp_W1, mlp_b1, mlp_W2, mlp_b2, out_W, out_b, out, G);
}